// Round 6
// baseline (604.718 us; speedup 1.0000x reference)
//
#include <hip/hip_runtime.h>
#include <math.h>

#define N0 32768
#define N1 8192
#define N2 2048
#define E0 262144
#define E1 65536
#define E2 16384
#define NTOT (N0+N1+N2)     // 43008 (multiple of 256)
#define ETOT (E0+E1+E2)     // 344064
#define NBLK (NTOT/256)     // 168
#define EPS 1e-9f

static inline int cdiv(int a, int b){ return (a + b - 1) / b; }

// bf16 pack (RNE) / unpack helpers
__device__ inline unsigned bfpack(float a, float b){
  unsigned ua = __float_as_uint(a), ub = __float_as_uint(b);
  ua = (ua + 0x7fffu + ((ua >> 16) & 1u)) >> 16;
  ub = (ub + 0x7fffu + ((ub >> 16) & 1u)) & 0xffff0000u;
  return ua | ub;
}
__device__ inline float bf_lo(unsigned d){ return __uint_as_float(d << 16); }
__device__ inline float bf_hi(unsigned d){ return __uint_as_float(d & 0xffff0000u); }

// ---------------- small utility kernels ----------------
__global__ void k_gather_pos(const float* __restrict__ pos, const int* __restrict__ idx,
                             float* __restrict__ out, int n){
  int i = blockIdx.x*256 + threadIdx.x;
  if (i < n){
    int s = idx[i];
    out[i*3+0] = pos[s*3+0];
    out[i*3+1] = pos[s*3+1];
    out[i*3+2] = pos[s*3+2];
  }
}
__global__ void k_inv_build(const int* __restrict__ fp, int* __restrict__ inv, int n2){
  int i = blockIdx.x*256 + threadIdx.x;
  if (i < n2) inv[fp[i]] = i;
}
// fused upsample: out = base + (inv>=0 ? up[inv] : 0)
__global__ void k_upsample(const float* __restrict__ base, const float* __restrict__ up,
                           const int* __restrict__ inv, float* __restrict__ out, int n){
  int t = blockIdx.x*256 + threadIdx.x;
  if (t < n*96){
    int nn = t / 96, j = t - nn*96;
    float v = base[t];
    int a = inv[nn];
    if (a >= 0) v += up[(size_t)a*96 + j];
    out[t] = v;
  }
}

// ---------------- concatenated CSR build ----------------
__global__ void k_countA(const int* __restrict__ d0, const int* __restrict__ d1,
                         const int* __restrict__ d2, int* cnt){
  int e = blockIdx.x*256 + threadIdx.x;
  if (e < E0)            atomicAdd(&cnt[d0[e]], 1);
  else if (e < E0+E1)    atomicAdd(&cnt[N0 + d1[e-E0]], 1);
  else if (e < ETOT)     atomicAdd(&cnt[N0+N1 + d2[e-E0-E1]], 1);
}
__global__ __launch_bounds__(256) void k_scan1(const int* __restrict__ cnt,
                                               int* __restrict__ excl,
                                               int* __restrict__ bsum){
  __shared__ int lds[256];
  int tid = threadIdx.x;
  int i = blockIdx.x*256 + tid;
  int v = cnt[i];
  lds[tid] = v;
  __syncthreads();
  for (int off = 1; off < 256; off <<= 1){
    int t = (tid >= off) ? lds[tid - off] : 0;
    __syncthreads();
    lds[tid] += t;
    __syncthreads();
  }
  excl[i] = lds[tid] - v;
  if (tid == 255) bsum[blockIdx.x] = lds[255];
}
__global__ __launch_bounds__(256) void k_scan2(int* bsum, int nb){
  __shared__ int lds[256];
  int tid = threadIdx.x;
  int v = (tid < nb) ? bsum[tid] : 0;
  lds[tid] = v;
  __syncthreads();
  for (int off = 1; off < 256; off <<= 1){
    int t = (tid >= off) ? lds[tid - off] : 0;
    __syncthreads();
    lds[tid] += t;
    __syncthreads();
  }
  if (tid < nb) bsum[tid] = lds[tid] - v;
}
__global__ __launch_bounds__(256) void k_scan3(const int* __restrict__ excl,
                                               const int* __restrict__ bsum,
                                               int* __restrict__ row,
                                               int* __restrict__ cur){
  int i = blockIdx.x*256 + threadIdx.x;
  int r = excl[i] + bsum[blockIdx.x];
  row[i] = r; cur[i] = r;
  if (i == 0) row[NTOT] = ETOT;
}
// scatter edge payload (src-local-id, meta float4{r,rel}) into global CSR order
__global__ void k_scatter_geoA(const int* __restrict__ s0, const int* __restrict__ d0,
                               const int* __restrict__ s1, const int* __restrict__ d1,
                               const int* __restrict__ s2, const int* __restrict__ d2,
                               const float* __restrict__ pos0, const float* __restrict__ pos1,
                               const float* __restrict__ pos2, int* cur,
                               int* __restrict__ srcs, float4* __restrict__ meta){
  int e = blockIdx.x*256 + threadIdx.x;
  if (e >= ETOT) return;
  int s, d, noff; const float* pos;
  if (e < E0)        { s = s0[e];        d = d0[e];        pos = pos0; noff = 0; }
  else if (e < E0+E1){ s = s1[e-E0];     d = d1[e-E0];     pos = pos1; noff = N0; }
  else               { s = s2[e-E0-E1];  d = d2[e-E0-E1];  pos = pos2; noff = N0+N1; }
  float dx = pos[d*3+0]-pos[s*3+0];
  float dy = pos[d*3+1]-pos[s*3+1];
  float dz = pos[d*3+2]-pos[s*3+2];
  int p = atomicAdd(&cur[noff + d], 1);
  srcs[p] = s;
  meta[p] = make_float4(sqrtf(dx*dx+dy*dy+dz*dz+1e-12f), dx, dy, dz);
}

// ---------------- per-layer transforms: q, packed-kv (bf16), skip ----------------
__global__ __launch_bounds__(256) void k_transform(
    const float* __restrict__ x,
    const float* __restrict__ Wq, const float* __restrict__ Wk,
    const float* __restrict__ Wv, const float* __restrict__ Ws,
    float* __restrict__ q, unsigned* __restrict__ kv,
    float* __restrict__ kf32, float* __restrict__ vf32,
    float* __restrict__ s,
    int n, int Cin, int Cout, int pack){
  __shared__ float w4[4][1024];
  __shared__ float xr[8][96];
  __shared__ float kvst[8][192];
  int tid = threadIdx.x;
  int nw = Cin * Cout;
  for (int i = tid; i < nw; i += 256){
    w4[0][i] = Wq[i]; w4[1][i] = Wk[i]; w4[2][i] = Wv[i]; w4[3][i] = Ws[i];
  }
  int g = tid >> 5, lane = tid & 31;
  int node = blockIdx.x*8 + g;
  int xl = Cin * 3;
  if (node < n){
    for (int j = lane; j < xl; j += 32) xr[g][j] = x[node*xl + j];
  }
  __syncthreads();
  if (node < n && lane < Cout){
    int OV = Cout*3;
    #pragma unroll
    for (int vv = 0; vv < 3; ++vv){
      float aq=0.f, ak=0.f, av=0.f, as=0.f;
      for (int c = 0; c < Cin; ++c){
        float xv = xr[g][c*3+vv];
        aq += xv * w4[0][c*Cout+lane];
        ak += xv * w4[1][c*Cout+lane];
        av += xv * w4[2][c*Cout+lane];
        as += xv * w4[3][c*Cout+lane];
      }
      int o = node*OV + lane*3 + vv;
      q[o]=aq; s[o]=as;
      if (pack){
        kvst[g][lane*3+vv] = ak;
        kvst[g][96 + lane*3+vv] = av;
      } else {
        kf32[o]=ak; vf32[o]=av;
      }
    }
  }
  if (pack){
    __syncthreads();
    if (node < n){
      #pragma unroll
      for (int t = 0; t < 3; ++t){
        int j = lane + 32*t;
        kv[node*96 + j] = bfpack(kvst[g][2*j], kvst[g][2*j+1]);
      }
    }
  }
}

// ---------------- fused attention (Cout=32, packed bf16 kv, 8-edge groups) ----------------
__global__ __launch_bounds__(256) void k_attn32(
    const float* __restrict__ qb, const unsigned* __restrict__ kvb,
    const float* __restrict__ sb,
    const int* __restrict__ row, const int* __restrict__ srcs,
    const float4* __restrict__ meta,
    const float* __restrict__ wr1, const float* __restrict__ wr2,
    const float* __restrict__ scaleA, const float* __restrict__ biasA,
    float* __restrict__ outb, int n, float invsc){
  __shared__ float vsum[8][96];
  int tid = threadIdx.x, g = tid >> 5, lane = tid & 31;
  int node = blockIdx.x*8 + g;
  bool act = node < n;
  float rw1 = (lane < 16) ? wr1[lane] : 0.f;
  float rw2 = (lane < 16) ? wr2[lane] : 0.f;
  float ql0=0.f, ql1=0.f, ql2=0.f, ql3=0.f;
  float z=0.f, av0=0.f, av1=0.f, av2=0.f, av3=0.f, R0=0.f, R1=0.f, R2=0.f;
  int beg=0, end=0;
  if (act){
    int nb = node*96;
    ql0 = qb[nb + 2*lane]*invsc;  ql1 = qb[nb + 2*lane+1]*invsc;
    if (lane < 16){ ql2 = qb[nb + 64 + 2*lane]*invsc; ql3 = qb[nb + 65 + 2*lane]*invsc; }
    beg = row[node]; end = row[node+1];
  }
  for (int cb = beg; cb < end; cb += 32){
    int csz = end - cb; if (csz > 32) csz = 32;
    int sn_l = 0; float4 mt = make_float4(0.f,0.f,0.f,0.f);
    if (lane < csz){
      int idx = cb + lane;
      sn_l = srcs[idx];
      mt = meta[idx];
    }
    for (int j = 0; j < csz; j += 8){
      int gs = csz - j; if (gs > 8) gs = 8;
      int sid[8]; float rrB[8];
      #pragma unroll
      for (int t = 0; t < 8; ++t){
        int sl = (j + t) & 31;
        sid[t] = __shfl(sn_l, sl, 32);
        rrB[t] = __shfl(mt.x, sl, 32);
      }
      // 24 independent lane-coalesced dword gathers per group (max MLP)
      unsigned d0[8], d1[8], d2[8];
      #pragma unroll
      for (int t = 0; t < 8; ++t){
        const unsigned* kp = kvb + (size_t)sid[t]*96;
        bool ok = t < gs;
        d0[t] = ok ? kp[lane]      : 0u;
        d1[t] = ok ? kp[lane+32]   : 0u;
        d2[t] = ok ? kp[lane+64]   : 0u;
      }
      #pragma unroll
      for (int t = 0; t < 8; ++t){
        float pt = bf_lo(d0[t])*ql0 + bf_hi(d0[t])*ql1;
        if (lane < 16) pt += bf_lo(d1[t])*ql2 + bf_hi(d1[t])*ql3;
        pt += fmaxf(rrB[t]*rw1, 0.f) * rw2;
        #pragma unroll
        for (int off = 16; off; off >>= 1) pt += __shfl_xor(pt, off, 32);
        float w = (t < gs) ? __expf(fminf(pt, 80.f)) : 0.f;
        z += w;
        av0 += w*bf_lo(d2[t]); av1 += w*bf_hi(d2[t]);
        if (lane >= 16){ av2 += w*bf_lo(d1[t]); av3 += w*bf_hi(d1[t]); }
        if (lane == j + t){ R0 += w*mt.y; R1 += w*mt.z; R2 += w*mt.w; }
      }
    }
  }
  #pragma unroll
  for (int off = 16; off; off >>= 1){
    R0 += __shfl_xor(R0, off, 32);
    R1 += __shfl_xor(R1, off, 32);
    R2 += __shfl_xor(R2, off, 32);
  }
  if (act){
    vsum[g][2*lane+32] = av0;
    vsum[g][2*lane+33] = av1;
    if (lane >= 16){ vsum[g][2*lane-32] = av2; vsum[g][2*lane-31] = av3; }
  }
  __syncthreads();
  if (act){
    float invz = 1.f / (z + EPS);
    int base = node*96 + 3*lane;
    float y0 = (vsum[g][3*lane+0] + R0)*invz + sb[base];
    float y1 = (vsum[g][3*lane+1] + R1)*invz + sb[base+1];
    float y2 = (vsum[g][3*lane+2] + R2)*invz + sb[base+2];
    float nrm = sqrtf(y0*y0 + y1*y1 + y2*y2 + 1e-12f);
    float f = fmaxf(scaleA[lane]*nrm + biasA[lane], 0.f) / nrm;
    outb[base]   = f*y0;
    outb[base+1] = f*y1;
    outb[base+2] = f*y2;
  }
}

// ---------------- specialized Cout=1 attention: one thread per node ----------------
__global__ __launch_bounds__(256) void k_attn1(
    const float* __restrict__ qb, const float* __restrict__ kb,
    const float* __restrict__ vb, const float* __restrict__ sb,
    const int* __restrict__ row, const int* __restrict__ srcs,
    const float4* __restrict__ meta,
    const float* __restrict__ wr1, const float* __restrict__ wr2,
    const float* __restrict__ scaleA, const float* __restrict__ biasA,
    float* __restrict__ outb, int n, float invsc){
  int i = blockIdx.x*256 + threadIdx.x;
  if (i >= n) return;
  float q0 = qb[i*3]*invsc, q1 = qb[i*3+1]*invsc, q2 = qb[i*3+2]*invsc;
  float z = 0.f, a0 = 0.f, a1 = 0.f, a2 = 0.f;
  int beg = row[i], end = row[i+1];
  for (int e = beg; e < end; ++e){
    int s = srcs[e];
    float4 m = meta[e];
    float k0 = kb[s*3], k1 = kb[s*3+1], k2 = kb[s*3+2];
    float v0 = vb[s*3], v1 = vb[s*3+1], v2 = vb[s*3+2];
    float pt = q0*k0 + q1*k1 + q2*k2;
    float rb = 0.f;
    #pragma unroll
    for (int jr = 0; jr < 16; ++jr) rb += fmaxf(m.x*wr1[jr], 0.f)*wr2[jr];
    pt += rb;
    float w = __expf(fminf(pt, 80.f));
    z += w;
    a0 += w*(v0 + m.y); a1 += w*(v1 + m.z); a2 += w*(v2 + m.w);
  }
  float invz = 1.f / (z + EPS);
  float y0 = a0*invz + sb[i*3];
  float y1 = a1*invz + sb[i*3+1];
  float y2 = a2*invz + sb[i*3+2];
  float nrm = sqrtf(y0*y0 + y1*y1 + y2*y2 + 1e-12f);
  float f = fmaxf(scaleA[0]*nrm + biasA[0], 0.f) / nrm;
  outb[i*3]   = f*y0;
  outb[i*3+1] = f*y1;
  outb[i*3+2] = f*y2;
}

// ---------------- pooling ----------------
__global__ void k_pool_add(const float* __restrict__ x, const int* __restrict__ cl,
                           float* sum, float* cnt, int n0){
  int t = blockIdx.x*256 + threadIdx.x;
  if (t < n0*96){
    int nn = t / 96, j = t - nn*96;
    int c = cl[nn];
    atomicAdd(&sum[c*96 + j], x[t]);
    if (j == 0) atomicAdd(&cnt[c], 1.f);
  }
}
__global__ void k_pool_div(const float* __restrict__ sum, const float* __restrict__ cnt,
                           float* __restrict__ out, int n1){
  int t = blockIdx.x*256 + threadIdx.x;
  if (t < n1*96) out[t] = sum[t] / (cnt[t/96] + EPS);
}

// ---------------- MLP head ----------------
__global__ void k_head(const float* __restrict__ x, const float* __restrict__ W,
                       float* __restrict__ out, int n){
  __shared__ float w[120];
  int tid = threadIdx.x;
  if (tid < 120) w[tid] = W[tid];
  __syncthreads();
  int idx = blockIdx.x*256 + tid;
  if (idx < n*40){
    int nn = idx / 40, o = idx - nn*40;
    float a = x[nn*3+0]*w[o] + x[nn*3+1]*w[40+o] + x[nn*3+2]*w[80+o];
    out[idx] = fmaxf(a, 0.f);
  }
}

extern "C" void kernel_launch(void* const* d_in, const int* in_sizes, int n_in,
                              void* d_out, int out_size, void* d_ws, size_t ws_size,
                              hipStream_t stream){
  const float* pos0      = (const float*)d_in[0];
  const float* v0        = (const float*)d_in[1];
  const float* Wq_first  = (const float*)d_in[2];
  const float* Wk_first  = (const float*)d_in[3];
  const float* Wv_first  = (const float*)d_in[4];
  const float* Ws_first  = (const float*)d_in[5];
  const float* Wq_mid    = (const float*)d_in[6];
  const float* Wk_mid    = (const float*)d_in[7];
  const float* Wv_mid    = (const float*)d_in[8];
  const float* Ws_mid    = (const float*)d_in[9];
  const float* Wq_last   = (const float*)d_in[10];
  const float* Wk_last   = (const float*)d_in[11];
  const float* Wv_last   = (const float*)d_in[12];
  const float* Ws_last   = (const float*)d_in[13];
  const float* wr1       = (const float*)d_in[14];
  const float* wr2       = (const float*)d_in[15];
  const float* scale_mid = (const float*)d_in[16];
  const float* bias_mid  = (const float*)d_in[17];
  const float* scale_last= (const float*)d_in[18];
  const float* bias_last = (const float*)d_in[19];
  const float* Wmlp      = (const float*)d_in[20];
  const int* src0 = (const int*)d_in[21];
  const int* dst0 = (const int*)d_in[22];
  const int* src1 = (const int*)d_in[23];
  const int* dst1 = (const int*)d_in[24];
  const int* src2 = (const int*)d_in[25];
  const int* dst2 = (const int*)d_in[26];
  const int* fp1  = (const int*)d_in[27];
  const int* fp2  = (const int*)d_in[28];
  const int* cl1  = (const int*)d_in[29];
  const int* cl2  = (const int*)d_in[30];

  float* ws = (float*)d_ws;
  size_t o = 0;
  float* xA   = ws + o; o += (size_t)N0*96;
  float* xB   = ws + o; o += (size_t)N0*96;
  float* x0s  = ws + o; o += (size_t)N0*96;
  float* x1s  = ws + o; o += (size_t)N1*96;
  float* qb   = ws + o; o += (size_t)N0*96;
  float* sb   = ws + o; o += (size_t)N0*96;
  unsigned* kvb = (unsigned*)(ws + o); o += (size_t)N0*96;
  float4* metaA = (float4*)(ws + o); o += (size_t)ETOT*4;
  float* kbf  = ws + o; o += (size_t)N0*3;
  float* vbf  = ws + o; o += (size_t)N0*3;
  float* pcnt = ws + o; o += N1;
  float* pos1 = ws + o; o += (size_t)N1*3;
  float* pos2 = ws + o; o += (size_t)N2*3;
  int* ib = (int*)(ws + o);
  size_t io = 0;
  int* rowA  = ib + io; io += NTOT+1;
  int* cntA  = ib + io; io += NTOT;
  int* curA  = ib + io; io += NTOT;
  int* exclA = ib + io; io += NTOT;
  int* bsumA = ib + io; io += 256;
  int* srcsA = ib + io; io += ETOT;
  int* inv0  = ib + io; io += N0;
  int* inv1  = ib + io; io += N1;

  k_gather_pos<<<cdiv(N1,256),256,0,stream>>>(pos0, fp1, pos1, N1);
  k_gather_pos<<<cdiv(N2,256),256,0,stream>>>(pos1, fp2, pos2, N2);

  // inverse maps for fused upsample
  hipMemsetAsync(inv0, 0xFF, N0*sizeof(int), stream);
  hipMemsetAsync(inv1, 0xFF, N1*sizeof(int), stream);
  k_inv_build<<<cdiv(N1,256),256,0,stream>>>(fp1, inv0, N1);
  k_inv_build<<<cdiv(N2,256),256,0,stream>>>(fp2, inv1, N2);

  hipMemsetAsync(cntA, 0, NTOT*sizeof(int), stream);
  k_countA<<<cdiv(ETOT,256),256,0,stream>>>(dst0, dst1, dst2, cntA);
  k_scan1<<<NBLK,256,0,stream>>>(cntA, exclA, bsumA);
  k_scan2<<<1,256,0,stream>>>(bsumA, NBLK);
  k_scan3<<<NBLK,256,0,stream>>>(exclA, bsumA, rowA, curA);
  k_scatter_geoA<<<cdiv(ETOT,256),256,0,stream>>>(src0, dst0, src1, dst1, src2, dst2,
                                                  pos0, pos1, pos2, curA, srcsA, metaA);

  auto layer32 = [&](const float* xin, int n, int nodeBase, int Cin,
                     const float* Wq_, const float* Wk_, const float* Wv_, const float* Ws_,
                     int lidx, const float* scale_, const float* bias_, float* xout){
    k_transform<<<cdiv(n,8),256,0,stream>>>(xin, Wq_, Wk_, Wv_, Ws_,
                                            qb, kvb, kbf, vbf, sb, n, Cin, 32, 1);
    float invsc = 1.f / sqrtf(96.f);
    k_attn32<<<cdiv(n,8),256,0,stream>>>(qb, kvb, sb, rowA + nodeBase, srcsA, metaA,
                                         wr1 + lidx*16, wr2 + lidx*16, scale_, bias_,
                                         xout, n, invsc);
  };

  const int C = 32;
  layer32(v0, N0, 0, 1, Wq_first, Wk_first, Wv_first, Ws_first,
          0, scale_mid + 0*C, bias_mid + 0*C, xA);
  layer32(xA, N0, 0, C, Wq_mid+0*1024, Wk_mid+0*1024, Wv_mid+0*1024, Ws_mid+0*1024,
          1, scale_mid + 1*C, bias_mid + 1*C, x0s);
  hipMemsetAsync(xA, 0, (size_t)N1*96*sizeof(float), stream);
  hipMemsetAsync(pcnt, 0, N1*sizeof(float), stream);
  k_pool_add<<<cdiv(N0*96,256),256,0,stream>>>(x0s, cl1, xA, pcnt, N0);
  k_pool_div<<<cdiv(N1*96,256),256,0,stream>>>(xA, pcnt, xB, N1);
  layer32(xB, N1, N0, C, Wq_mid+1*1024, Wk_mid+1*1024, Wv_mid+1*1024, Ws_mid+1*1024,
          2, scale_mid + 2*C, bias_mid + 2*C, xA);
  layer32(xA, N1, N0, C, Wq_mid+2*1024, Wk_mid+2*1024, Wv_mid+2*1024, Ws_mid+2*1024,
          3, scale_mid + 3*C, bias_mid + 3*C, x1s);
  hipMemsetAsync(xA, 0, (size_t)N2*96*sizeof(float), stream);
  hipMemsetAsync(pcnt, 0, N2*sizeof(float), stream);
  k_pool_add<<<cdiv(N1*96,256),256,0,stream>>>(x1s, cl2, xA, pcnt, N1);
  k_pool_div<<<cdiv(N2*96,256),256,0,stream>>>(xA, pcnt, xB, N2);
  layer32(xB, N2, N0+N1, C, Wq_mid+3*1024, Wk_mid+3*1024, Wv_mid+3*1024, Ws_mid+3*1024,
          4, scale_mid + 4*C, bias_mid + 4*C, xA);
  layer32(xA, N2, N0+N1, C, Wq_mid+4*1024, Wk_mid+4*1024, Wv_mid+4*1024, Ws_mid+4*1024,
          5, scale_mid + 5*C, bias_mid + 5*C, xB);
  // fused upsample level2 -> level1 : xA = x1s + scatter(xB)
  k_upsample<<<cdiv(N1*96,256),256,0,stream>>>(x1s, xB, inv1, xA, N1);
  layer32(xA, N1, N0, C, Wq_mid+5*1024, Wk_mid+5*1024, Wv_mid+5*1024, Ws_mid+5*1024,
          6, scale_mid + 6*C, bias_mid + 6*C, xB);
  layer32(xB, N1, N0, C, Wq_mid+6*1024, Wk_mid+6*1024, Wv_mid+6*1024, Ws_mid+6*1024,
          7, scale_mid + 7*C, bias_mid + 7*C, xA);
  // fused upsample level1 -> level0 : xB = x0s + scatter(xA)
  k_upsample<<<cdiv(N0*96,256),256,0,stream>>>(x0s, xA, inv0, xB, N0);
  layer32(xB, N0, 0, C, Wq_mid+7*1024, Wk_mid+7*1024, Wv_mid+7*1024, Ws_mid+7*1024,
          8, scale_mid + 8*C, bias_mid + 8*C, xA);
  // L9 (Cout=1): transform (fp32 kv) + per-node scalar attention
  k_transform<<<cdiv(N0,8),256,0,stream>>>(xA, Wq_last, Wk_last, Wv_last, Ws_last,
                                           qb, kvb, kbf, vbf, sb, N0, C, 1, 0);
  {
    float invsc = 1.f / sqrtf(3.f);
    k_attn1<<<cdiv(N0,256),256,0,stream>>>(qb, kbf, vbf, sb, rowA, srcsA, metaA,
                                           wr1 + 9*16, wr2 + 9*16, scale_last, bias_last,
                                           xB, N0, invsc);
  }
  k_head<<<cdiv(N0*40,256),256,0,stream>>>(xB, Wmlp, (float*)d_out, N0);
}

// Round 7
// 599.538 us; speedup vs baseline: 1.0086x; 1.0086x over previous
//
#include <hip/hip_runtime.h>
#include <math.h>

#define N0 32768
#define N1 8192
#define N2 2048
#define E0 262144
#define E1 65536
#define E2 16384
#define NTOT (N0+N1+N2)     // 43008 (multiple of 256)
#define ETOT (E0+E1+E2)     // 344064
#define NBLK (NTOT/256)     // 168
#define EPS 1e-9f

static inline int cdiv(int a, int b){ return (a + b - 1) / b; }

// bf16 pack (RNE) / unpack helpers
__device__ inline unsigned bfpack(float a, float b){
  unsigned ua = __float_as_uint(a), ub = __float_as_uint(b);
  ua = (ua + 0x7fffu + ((ua >> 16) & 1u)) >> 16;
  ub = (ub + 0x7fffu + ((ub >> 16) & 1u)) & 0xffff0000u;
  return ua | ub;
}
__device__ inline float bf_lo(unsigned d){ return __uint_as_float(d << 16); }
__device__ inline float bf_hi(unsigned d){ return __uint_as_float(d & 0xffff0000u); }

// ---------------- small utility kernels ----------------
__global__ void k_gather_pos(const float* __restrict__ pos, const int* __restrict__ idx,
                             float* __restrict__ out, int n){
  int i = blockIdx.x*256 + threadIdx.x;
  if (i < n){
    int s = idx[i];
    out[i*3+0] = pos[s*3+0];
    out[i*3+1] = pos[s*3+1];
    out[i*3+2] = pos[s*3+2];
  }
}
__global__ void k_inv_build(const int* __restrict__ fp, int* __restrict__ inv, int n2){
  int i = blockIdx.x*256 + threadIdx.x;
  if (i < n2) inv[fp[i]] = i;
}
// fused upsample: out = base + (inv>=0 ? up[inv] : 0)
__global__ void k_upsample(const float* __restrict__ base, const float* __restrict__ up,
                           const int* __restrict__ inv, float* __restrict__ out, int n){
  int t = blockIdx.x*256 + threadIdx.x;
  if (t < n*96){
    int nn = t / 96, j = t - nn*96;
    float v = base[t];
    int a = inv[nn];
    if (a >= 0) v += up[(size_t)a*96 + j];
    out[t] = v;
  }
}

// ---------------- concatenated CSR build ----------------
__global__ void k_countA(const int* __restrict__ d0, const int* __restrict__ d1,
                         const int* __restrict__ d2, int* cnt){
  int e = blockIdx.x*256 + threadIdx.x;
  if (e < E0)            atomicAdd(&cnt[d0[e]], 1);
  else if (e < E0+E1)    atomicAdd(&cnt[N0 + d1[e-E0]], 1);
  else if (e < ETOT)     atomicAdd(&cnt[N0+N1 + d2[e-E0-E1]], 1);
}
__global__ __launch_bounds__(256) void k_scan1(const int* __restrict__ cnt,
                                               int* __restrict__ excl,
                                               int* __restrict__ bsum){
  __shared__ int lds[256];
  int tid = threadIdx.x;
  int i = blockIdx.x*256 + tid;
  int v = cnt[i];
  lds[tid] = v;
  __syncthreads();
  for (int off = 1; off < 256; off <<= 1){
    int t = (tid >= off) ? lds[tid - off] : 0;
    __syncthreads();
    lds[tid] += t;
    __syncthreads();
  }
  excl[i] = lds[tid] - v;
  if (tid == 255) bsum[blockIdx.x] = lds[255];
}
__global__ __launch_bounds__(256) void k_scan2(int* bsum, int nb){
  __shared__ int lds[256];
  int tid = threadIdx.x;
  int v = (tid < nb) ? bsum[tid] : 0;
  lds[tid] = v;
  __syncthreads();
  for (int off = 1; off < 256; off <<= 1){
    int t = (tid >= off) ? lds[tid - off] : 0;
    __syncthreads();
    lds[tid] += t;
    __syncthreads();
  }
  if (tid < nb) bsum[tid] = lds[tid] - v;
}
__global__ __launch_bounds__(256) void k_scan3(const int* __restrict__ excl,
                                               const int* __restrict__ bsum,
                                               int* __restrict__ row,
                                               int* __restrict__ cur){
  int i = blockIdx.x*256 + threadIdx.x;
  int r = excl[i] + bsum[blockIdx.x];
  row[i] = r; cur[i] = r;
  if (i == 0) row[NTOT] = ETOT;
}
// scatter edge payload (src-local-id, meta float4{r,rel}) into global CSR order
__global__ void k_scatter_geoA(const int* __restrict__ s0, const int* __restrict__ d0,
                               const int* __restrict__ s1, const int* __restrict__ d1,
                               const int* __restrict__ s2, const int* __restrict__ d2,
                               const float* __restrict__ pos0, const float* __restrict__ pos1,
                               const float* __restrict__ pos2, int* cur,
                               int* __restrict__ srcs, float4* __restrict__ meta){
  int e = blockIdx.x*256 + threadIdx.x;
  if (e >= ETOT) return;
  int s, d, noff; const float* pos;
  if (e < E0)        { s = s0[e];        d = d0[e];        pos = pos0; noff = 0; }
  else if (e < E0+E1){ s = s1[e-E0];     d = d1[e-E0];     pos = pos1; noff = N0; }
  else               { s = s2[e-E0-E1];  d = d2[e-E0-E1];  pos = pos2; noff = N0+N1; }
  float dx = pos[d*3+0]-pos[s*3+0];
  float dy = pos[d*3+1]-pos[s*3+1];
  float dz = pos[d*3+2]-pos[s*3+2];
  int p = atomicAdd(&cur[noff + d], 1);
  srcs[p] = s;
  meta[p] = make_float4(sqrtf(dx*dx+dy*dy+dz*dz+1e-12f), dx, dy, dz);
}

// ---------------- per-layer transforms: q, packed-kv (bf16), skip ----------------
__global__ __launch_bounds__(256) void k_transform(
    const float* __restrict__ x,
    const float* __restrict__ Wq, const float* __restrict__ Wk,
    const float* __restrict__ Wv, const float* __restrict__ Ws,
    float* __restrict__ q, unsigned* __restrict__ kv,
    float* __restrict__ kf32, float* __restrict__ vf32,
    float* __restrict__ s,
    int n, int Cin, int Cout, int pack){
  __shared__ float w4[4][1024];
  __shared__ float xr[8][96];
  __shared__ float kvst[8][192];
  int tid = threadIdx.x;
  int nw = Cin * Cout;
  for (int i = tid; i < nw; i += 256){
    w4[0][i] = Wq[i]; w4[1][i] = Wk[i]; w4[2][i] = Wv[i]; w4[3][i] = Ws[i];
  }
  int g = tid >> 5, lane = tid & 31;
  int node = blockIdx.x*8 + g;
  int xl = Cin * 3;
  if (node < n){
    for (int j = lane; j < xl; j += 32) xr[g][j] = x[node*xl + j];
  }
  __syncthreads();
  if (node < n && lane < Cout){
    int OV = Cout*3;
    #pragma unroll
    for (int vv = 0; vv < 3; ++vv){
      float aq=0.f, ak=0.f, av=0.f, as=0.f;
      for (int c = 0; c < Cin; ++c){
        float xv = xr[g][c*3+vv];
        aq += xv * w4[0][c*Cout+lane];
        ak += xv * w4[1][c*Cout+lane];
        av += xv * w4[2][c*Cout+lane];
        as += xv * w4[3][c*Cout+lane];
      }
      int o = node*OV + lane*3 + vv;
      q[o]=aq; s[o]=as;
      if (pack){
        kvst[g][lane*3+vv] = ak;
        kvst[g][96 + lane*3+vv] = av;
      } else {
        kf32[o]=ak; vf32[o]=av;
      }
    }
  }
  if (pack){
    __syncthreads();
    if (node < n){
      #pragma unroll
      for (int t = 0; t < 3; ++t){
        int j = lane + 32*t;
        kv[node*96 + j] = bfpack(kvst[g][2*j], kvst[g][2*j+1]);
      }
    }
  }
}

// ---------------- fused attention (Cout=32, packed bf16 kv) ----------------
// 4-edge groups, software double-buffer: prefetch group j+4 while computing j
__global__ __launch_bounds__(256) void k_attn32(
    const float* __restrict__ qb, const unsigned* __restrict__ kvb,
    const float* __restrict__ sb,
    const int* __restrict__ row, const int* __restrict__ srcs,
    const float4* __restrict__ meta,
    const float* __restrict__ wr1, const float* __restrict__ wr2,
    const float* __restrict__ scaleA, const float* __restrict__ biasA,
    float* __restrict__ outb, int n, float invsc){
  __shared__ float vsum[8][96];
  int tid = threadIdx.x, g = tid >> 5, lane = tid & 31;
  int node = blockIdx.x*8 + g;
  bool act = node < n;
  float rw1 = (lane < 16) ? wr1[lane] : 0.f;
  float rw2 = (lane < 16) ? wr2[lane] : 0.f;
  float ql0=0.f, ql1=0.f, ql2=0.f, ql3=0.f;
  float z=0.f, av0=0.f, av1=0.f, av2=0.f, av3=0.f, R0=0.f, R1=0.f, R2=0.f;
  int beg=0, end=0;
  if (act){
    int nb = node*96;
    ql0 = qb[nb + 2*lane]*invsc;  ql1 = qb[nb + 2*lane+1]*invsc;
    if (lane < 16){ ql2 = qb[nb + 64 + 2*lane]*invsc; ql3 = qb[nb + 65 + 2*lane]*invsc; }
    beg = row[node]; end = row[node+1];
  }
  for (int cb = beg; cb < end; cb += 32){
    int csz = end - cb; if (csz > 32) csz = 32;
    int sn_l = 0; float4 mt = make_float4(0.f,0.f,0.f,0.f);
    if (lane < csz){
      int idx = cb + lane;
      sn_l = srcs[idx];
      mt = meta[idx];
    }
    // prefetch group 0
    unsigned A0[4], A1[4], A2[4]; float Ar[4];
    {
      int ags = csz < 4 ? csz : 4;
      #pragma unroll
      for (int t = 0; t < 4; ++t){
        int sd = __shfl(sn_l, t, 32);
        Ar[t]  = __shfl(mt.x, t, 32);
        const unsigned* kp = kvb + (size_t)sd*96;
        bool ok = t < ags;
        A0[t] = ok ? kp[lane]    : 0u;
        A1[t] = ok ? kp[lane+32] : 0u;
        A2[t] = ok ? kp[lane+64] : 0u;
      }
    }
    for (int j = 0; j < csz; j += 4){
      int nj = j + 4;
      // prefetch next group
      unsigned B0[4], B1[4], B2[4]; float Br[4];
      {
        int bgs = csz - nj; if (bgs > 4) bgs = 4;
        #pragma unroll
        for (int t = 0; t < 4; ++t){
          int sl = (nj + t) & 31;
          int sd = __shfl(sn_l, sl, 32);
          Br[t]  = __shfl(mt.x, sl, 32);
          const unsigned* kp = kvb + (size_t)sd*96;
          bool ok = t < bgs;
          B0[t] = ok ? kp[lane]    : 0u;
          B1[t] = ok ? kp[lane+32] : 0u;
          B2[t] = ok ? kp[lane+64] : 0u;
        }
      }
      // compute current group
      int gs = csz - j; if (gs > 4) gs = 4;
      #pragma unroll
      for (int t = 0; t < 4; ++t){
        float pt = bf_lo(A0[t])*ql0 + bf_hi(A0[t])*ql1;
        if (lane < 16) pt += bf_lo(A1[t])*ql2 + bf_hi(A1[t])*ql3;
        pt += fmaxf(Ar[t]*rw1, 0.f) * rw2;
        #pragma unroll
        for (int off = 16; off; off >>= 1) pt += __shfl_xor(pt, off, 32);
        float w = (t < gs) ? __expf(fminf(pt, 80.f)) : 0.f;
        z += w;
        av0 += w*bf_lo(A2[t]); av1 += w*bf_hi(A2[t]);
        if (lane >= 16){ av2 += w*bf_lo(A1[t]); av3 += w*bf_hi(A1[t]); }
        if (lane == j + t){ R0 += w*mt.y; R1 += w*mt.z; R2 += w*mt.w; }
      }
      #pragma unroll
      for (int t = 0; t < 4; ++t){ A0[t]=B0[t]; A1[t]=B1[t]; A2[t]=B2[t]; Ar[t]=Br[t]; }
    }
  }
  #pragma unroll
  for (int off = 16; off; off >>= 1){
    R0 += __shfl_xor(R0, off, 32);
    R1 += __shfl_xor(R1, off, 32);
    R2 += __shfl_xor(R2, off, 32);
  }
  if (act){
    vsum[g][2*lane+32] = av0;
    vsum[g][2*lane+33] = av1;
    if (lane >= 16){ vsum[g][2*lane-32] = av2; vsum[g][2*lane-31] = av3; }
  }
  __syncthreads();
  if (act){
    float invz = 1.f / (z + EPS);
    int base = node*96 + 3*lane;
    float y0 = (vsum[g][3*lane+0] + R0)*invz + sb[base];
    float y1 = (vsum[g][3*lane+1] + R1)*invz + sb[base+1];
    float y2 = (vsum[g][3*lane+2] + R2)*invz + sb[base+2];
    float nrm = sqrtf(y0*y0 + y1*y1 + y2*y2 + 1e-12f);
    float f = fmaxf(scaleA[lane]*nrm + biasA[lane], 0.f) / nrm;
    outb[base]   = f*y0;
    outb[base+1] = f*y1;
    outb[base+2] = f*y2;
  }
}

// ---------------- Cout=1 attention fused with MLP head: one thread per node ----------------
__global__ __launch_bounds__(256) void k_attn1_head(
    const float* __restrict__ qb, const float* __restrict__ kb,
    const float* __restrict__ vb, const float* __restrict__ sb,
    const int* __restrict__ row, const int* __restrict__ srcs,
    const float4* __restrict__ meta,
    const float* __restrict__ wr1, const float* __restrict__ wr2,
    const float* __restrict__ scaleA, const float* __restrict__ biasA,
    const float* __restrict__ Wmlp,
    float* __restrict__ out, int n, float invsc){
  __shared__ float w[120];
  int tid = threadIdx.x;
  if (tid < 120) w[tid] = Wmlp[tid];
  __syncthreads();
  int i = blockIdx.x*256 + tid;
  if (i >= n) return;
  float q0 = qb[i*3]*invsc, q1 = qb[i*3+1]*invsc, q2 = qb[i*3+2]*invsc;
  float z = 0.f, a0 = 0.f, a1 = 0.f, a2 = 0.f;
  int beg = row[i], end = row[i+1];
  for (int e = beg; e < end; ++e){
    int s = srcs[e];
    float4 m = meta[e];
    float k0 = kb[s*3], k1 = kb[s*3+1], k2 = kb[s*3+2];
    float v0 = vb[s*3], v1 = vb[s*3+1], v2 = vb[s*3+2];
    float pt = q0*k0 + q1*k1 + q2*k2;
    float rb = 0.f;
    #pragma unroll
    for (int jr = 0; jr < 16; ++jr) rb += fmaxf(m.x*wr1[jr], 0.f)*wr2[jr];
    pt += rb;
    float wgt = __expf(fminf(pt, 80.f));
    z += wgt;
    a0 += wgt*(v0 + m.y); a1 += wgt*(v1 + m.z); a2 += wgt*(v2 + m.w);
  }
  float invz = 1.f / (z + EPS);
  float y0 = a0*invz + sb[i*3];
  float y1 = a1*invz + sb[i*3+1];
  float y2 = a2*invz + sb[i*3+2];
  float nrm = sqrtf(y0*y0 + y1*y1 + y2*y2 + 1e-12f);
  float f = fmaxf(scaleA[0]*nrm + biasA[0], 0.f) / nrm;
  y0 *= f; y1 *= f; y2 *= f;
  #pragma unroll
  for (int o2 = 0; o2 < 40; ++o2){
    out[(size_t)i*40 + o2] = fmaxf(y0*w[o2] + y1*w[40+o2] + y2*w[80+o2], 0.f);
  }
}

// ---------------- pooling ----------------
__global__ void k_pool_add(const float* __restrict__ x, const int* __restrict__ cl,
                           float* sum, float* cnt, int n0){
  int t = blockIdx.x*256 + threadIdx.x;
  if (t < n0*96){
    int nn = t / 96, j = t - nn*96;
    int c = cl[nn];
    atomicAdd(&sum[c*96 + j], x[t]);
    if (j == 0) atomicAdd(&cnt[c], 1.f);
  }
}
__global__ void k_pool_div(const float* __restrict__ sum, const float* __restrict__ cnt,
                           float* __restrict__ out, int n1){
  int t = blockIdx.x*256 + threadIdx.x;
  if (t < n1*96) out[t] = sum[t] / (cnt[t/96] + EPS);
}

extern "C" void kernel_launch(void* const* d_in, const int* in_sizes, int n_in,
                              void* d_out, int out_size, void* d_ws, size_t ws_size,
                              hipStream_t stream){
  const float* pos0      = (const float*)d_in[0];
  const float* v0        = (const float*)d_in[1];
  const float* Wq_first  = (const float*)d_in[2];
  const float* Wk_first  = (const float*)d_in[3];
  const float* Wv_first  = (const float*)d_in[4];
  const float* Ws_first  = (const float*)d_in[5];
  const float* Wq_mid    = (const float*)d_in[6];
  const float* Wk_mid    = (const float*)d_in[7];
  const float* Wv_mid    = (const float*)d_in[8];
  const float* Ws_mid    = (const float*)d_in[9];
  const float* Wq_last   = (const float*)d_in[10];
  const float* Wk_last   = (const float*)d_in[11];
  const float* Wv_last   = (const float*)d_in[12];
  const float* Ws_last   = (const float*)d_in[13];
  const float* wr1       = (const float*)d_in[14];
  const float* wr2       = (const float*)d_in[15];
  const float* scale_mid = (const float*)d_in[16];
  const float* bias_mid  = (const float*)d_in[17];
  const float* scale_last= (const float*)d_in[18];
  const float* bias_last = (const float*)d_in[19];
  const float* Wmlp      = (const float*)d_in[20];
  const int* src0 = (const int*)d_in[21];
  const int* dst0 = (const int*)d_in[22];
  const int* src1 = (const int*)d_in[23];
  const int* dst1 = (const int*)d_in[24];
  const int* src2 = (const int*)d_in[25];
  const int* dst2 = (const int*)d_in[26];
  const int* fp1  = (const int*)d_in[27];
  const int* fp2  = (const int*)d_in[28];
  const int* cl1  = (const int*)d_in[29];
  const int* cl2  = (const int*)d_in[30];

  float* ws = (float*)d_ws;
  size_t o = 0;
  float* xA   = ws + o; o += (size_t)N0*96;
  float* xB   = ws + o; o += (size_t)N0*96;
  float* x0s  = ws + o; o += (size_t)N0*96;
  float* x1s  = ws + o; o += (size_t)N1*96;
  float* qb   = ws + o; o += (size_t)N0*96;
  float* sb   = ws + o; o += (size_t)N0*96;
  unsigned* kvb = (unsigned*)(ws + o); o += (size_t)N0*96;
  float4* metaA = (float4*)(ws + o); o += (size_t)ETOT*4;
  float* kbf  = ws + o; o += (size_t)N0*3;
  float* vbf  = ws + o; o += (size_t)N0*3;
  float* pcnt = ws + o; o += N1;
  float* pos1 = ws + o; o += (size_t)N1*3;
  float* pos2 = ws + o; o += (size_t)N2*3;
  int* ib = (int*)(ws + o);
  size_t io = 0;
  int* rowA  = ib + io; io += NTOT+1;
  int* cntA  = ib + io; io += NTOT;
  int* curA  = ib + io; io += NTOT;
  int* exclA = ib + io; io += NTOT;
  int* bsumA = ib + io; io += 256;
  int* srcsA = ib + io; io += ETOT;
  int* inv0  = ib + io; io += N0;
  int* inv1  = ib + io; io += N1;

  k_gather_pos<<<cdiv(N1,256),256,0,stream>>>(pos0, fp1, pos1, N1);
  k_gather_pos<<<cdiv(N2,256),256,0,stream>>>(pos1, fp2, pos2, N2);

  // inverse maps for fused upsample
  hipMemsetAsync(inv0, 0xFF, N0*sizeof(int), stream);
  hipMemsetAsync(inv1, 0xFF, N1*sizeof(int), stream);
  k_inv_build<<<cdiv(N1,256),256,0,stream>>>(fp1, inv0, N1);
  k_inv_build<<<cdiv(N2,256),256,0,stream>>>(fp2, inv1, N2);

  hipMemsetAsync(cntA, 0, NTOT*sizeof(int), stream);
  k_countA<<<cdiv(ETOT,256),256,0,stream>>>(dst0, dst1, dst2, cntA);
  k_scan1<<<NBLK,256,0,stream>>>(cntA, exclA, bsumA);
  k_scan2<<<1,256,0,stream>>>(bsumA, NBLK);
  k_scan3<<<NBLK,256,0,stream>>>(exclA, bsumA, rowA, curA);
  k_scatter_geoA<<<cdiv(ETOT,256),256,0,stream>>>(src0, dst0, src1, dst1, src2, dst2,
                                                  pos0, pos1, pos2, curA, srcsA, metaA);

  auto layer32 = [&](const float* xin, int n, int nodeBase, int Cin,
                     const float* Wq_, const float* Wk_, const float* Wv_, const float* Ws_,
                     int lidx, const float* scale_, const float* bias_, float* xout){
    k_transform<<<cdiv(n,8),256,0,stream>>>(xin, Wq_, Wk_, Wv_, Ws_,
                                            qb, kvb, kbf, vbf, sb, n, Cin, 32, 1);
    float invsc = 1.f / sqrtf(96.f);
    k_attn32<<<cdiv(n,8),256,0,stream>>>(qb, kvb, sb, rowA + nodeBase, srcsA, metaA,
                                         wr1 + lidx*16, wr2 + lidx*16, scale_, bias_,
                                         xout, n, invsc);
  };

  const int C = 32;
  layer32(v0, N0, 0, 1, Wq_first, Wk_first, Wv_first, Ws_first,
          0, scale_mid + 0*C, bias_mid + 0*C, xA);
  layer32(xA, N0, 0, C, Wq_mid+0*1024, Wk_mid+0*1024, Wv_mid+0*1024, Ws_mid+0*1024,
          1, scale_mid + 1*C, bias_mid + 1*C, x0s);
  hipMemsetAsync(xA, 0, (size_t)N1*96*sizeof(float), stream);
  hipMemsetAsync(pcnt, 0, N1*sizeof(float), stream);
  k_pool_add<<<cdiv(N0*96,256),256,0,stream>>>(x0s, cl1, xA, pcnt, N0);
  k_pool_div<<<cdiv(N1*96,256),256,0,stream>>>(xA, pcnt, xB, N1);
  layer32(xB, N1, N0, C, Wq_mid+1*1024, Wk_mid+1*1024, Wv_mid+1*1024, Ws_mid+1*1024,
          2, scale_mid + 2*C, bias_mid + 2*C, xA);
  layer32(xA, N1, N0, C, Wq_mid+2*1024, Wk_mid+2*1024, Wv_mid+2*1024, Ws_mid+2*1024,
          3, scale_mid + 3*C, bias_mid + 3*C, x1s);
  hipMemsetAsync(xA, 0, (size_t)N2*96*sizeof(float), stream);
  hipMemsetAsync(pcnt, 0, N2*sizeof(float), stream);
  k_pool_add<<<cdiv(N1*96,256),256,0,stream>>>(x1s, cl2, xA, pcnt, N1);
  k_pool_div<<<cdiv(N2*96,256),256,0,stream>>>(xA, pcnt, xB, N2);
  layer32(xB, N2, N0+N1, C, Wq_mid+3*1024, Wk_mid+3*1024, Wv_mid+3*1024, Ws_mid+3*1024,
          4, scale_mid + 4*C, bias_mid + 4*C, xA);
  layer32(xA, N2, N0+N1, C, Wq_mid+4*1024, Wk_mid+4*1024, Wv_mid+4*1024, Ws_mid+4*1024,
          5, scale_mid + 5*C, bias_mid + 5*C, xB);
  // fused upsample level2 -> level1 : xA = x1s + scatter(xB)
  k_upsample<<<cdiv(N1*96,256),256,0,stream>>>(x1s, xB, inv1, xA, N1);
  layer32(xA, N1, N0, C, Wq_mid+5*1024, Wk_mid+5*1024, Wv_mid+5*1024, Ws_mid+5*1024,
          6, scale_mid + 6*C, bias_mid + 6*C, xB);
  layer32(xB, N1, N0, C, Wq_mid+6*1024, Wk_mid+6*1024, Wv_mid+6*1024, Ws_mid+6*1024,
          7, scale_mid + 7*C, bias_mid + 7*C, xA);
  // fused upsample level1 -> level0 : xB = x0s + scatter(xA)
  k_upsample<<<cdiv(N0*96,256),256,0,stream>>>(x0s, xA, inv0, xB, N0);
  layer32(xB, N0, 0, C, Wq_mid+7*1024, Wk_mid+7*1024, Wv_mid+7*1024, Ws_mid+7*1024,
          8, scale_mid + 8*C, bias_mid + 8*C, xA);
  // L9 (Cout=1): transform (fp32 kv) + per-node scalar attention fused with head
  k_transform<<<cdiv(N0,8),256,0,stream>>>(xA, Wq_last, Wk_last, Wv_last, Ws_last,
                                           qb, kvb, kbf, vbf, sb, N0, C, 1, 0);
  {
    float invsc = 1.f / sqrtf(3.f);
    k_attn1_head<<<cdiv(N0,256),256,0,stream>>>(qb, kbf, vbf, sb, rowA, srcsA, metaA,
                                                wr1 + 9*16, wr2 + 9*16, scale_last, bias_last,
                                                Wmlp, (float*)d_out, N0, invsc);
  }
}

// Round 8
// 506.949 us; speedup vs baseline: 1.1929x; 1.1826x over previous
//
#include <hip/hip_runtime.h>
#include <math.h>

#define N0 32768
#define N1 8192
#define N2 2048
#define E0 262144
#define E1 65536
#define E2 16384
#define NTOT (N0+N1+N2)     // 43008
#define ETOT (E0+E1+E2)     // 344064
#define NBLK (NTOT/256)     // 168
#define EPS 1e-9f

static inline int cdiv(int a, int b){ return (a + b - 1) / b; }

__device__ inline unsigned bfpack(float a, float b){
  unsigned ua = __float_as_uint(a), ub = __float_as_uint(b);
  ua = (ua + 0x7fffu + ((ua >> 16) & 1u)) >> 16;
  ub = (ub + 0x7fffu + ((ub >> 16) & 1u)) & 0xffff0000u;
  return ua | ub;
}
__device__ inline float bf_lo(unsigned d){ return __uint_as_float(d << 16); }
__device__ inline float bf_hi(unsigned d){ return __uint_as_float(d & 0xffff0000u); }

// ---------------- small utility kernels ----------------
__global__ void k_gather_pos(const float* __restrict__ pos, const int* __restrict__ idx,
                             float* __restrict__ out, int n){
  int i = blockIdx.x*256 + threadIdx.x;
  if (i < n){
    int s = idx[i];
    out[i*3+0] = pos[s*3+0];
    out[i*3+1] = pos[s*3+1];
    out[i*3+2] = pos[s*3+2];
  }
}
__global__ void k_inv_build(const int* __restrict__ fp, int* __restrict__ inv, int n2){
  int i = blockIdx.x*256 + threadIdx.x;
  if (i < n2) inv[fp[i]] = i;
}
__global__ void k_upsample(const float* __restrict__ base, const float* __restrict__ up,
                           const int* __restrict__ inv, float* __restrict__ out, int n){
  int t = blockIdx.x*256 + threadIdx.x;
  if (t < n*96){
    int nn = t / 96, j = t - nn*96;
    float v = base[t];
    int a = inv[nn];
    if (a >= 0) v += up[(size_t)a*96 + j];
    out[t] = v;
  }
}

// ---------------- concatenated CSR build ----------------
__global__ void k_countA(const int* __restrict__ d0, const int* __restrict__ d1,
                         const int* __restrict__ d2, int* cnt){
  int e = blockIdx.x*256 + threadIdx.x;
  if (e < E0)            atomicAdd(&cnt[d0[e]], 1);
  else if (e < E0+E1)    atomicAdd(&cnt[N0 + d1[e-E0]], 1);
  else if (e < ETOT)     atomicAdd(&cnt[N0+N1 + d2[e-E0-E1]], 1);
}
__global__ __launch_bounds__(256) void k_scan1(const int* __restrict__ cnt,
                                               int* __restrict__ excl,
                                               int* __restrict__ bsum){
  __shared__ int lds[256];
  int tid = threadIdx.x;
  int i = blockIdx.x*256 + tid;
  int v = cnt[i];
  lds[tid] = v;
  __syncthreads();
  for (int off = 1; off < 256; off <<= 1){
    int t = (tid >= off) ? lds[tid - off] : 0;
    __syncthreads();
    lds[tid] += t;
    __syncthreads();
  }
  excl[i] = lds[tid] - v;
  if (tid == 255) bsum[blockIdx.x] = lds[255];
}
__global__ __launch_bounds__(256) void k_scan2(int* bsum, int nb){
  __shared__ int lds[256];
  int tid = threadIdx.x;
  int v = (tid < nb) ? bsum[tid] : 0;
  lds[tid] = v;
  __syncthreads();
  for (int off = 1; off < 256; off <<= 1){
    int t = (tid >= off) ? lds[tid - off] : 0;
    __syncthreads();
    lds[tid] += t;
    __syncthreads();
  }
  if (tid < nb) bsum[tid] = lds[tid] - v;
}
__global__ __launch_bounds__(256) void k_scan3(const int* __restrict__ excl,
                                               const int* __restrict__ bsum,
                                               int* __restrict__ row,
                                               int* __restrict__ cur){
  int i = blockIdx.x*256 + threadIdx.x;
  int r = excl[i] + bsum[blockIdx.x];
  row[i] = r; cur[i] = r;
  if (i == 0) row[NTOT] = ETOT;
}
__global__ void k_scatter_geoA(const int* __restrict__ s0, const int* __restrict__ d0,
                               const int* __restrict__ s1, const int* __restrict__ d1,
                               const int* __restrict__ s2, const int* __restrict__ d2,
                               const float* __restrict__ pos0, const float* __restrict__ pos1,
                               const float* __restrict__ pos2, int* cur,
                               int* __restrict__ srcs, float4* __restrict__ meta){
  int e = blockIdx.x*256 + threadIdx.x;
  if (e >= ETOT) return;
  int s, d, noff; const float* pos;
  if (e < E0)        { s = s0[e];        d = d0[e];        pos = pos0; noff = 0; }
  else if (e < E0+E1){ s = s1[e-E0];     d = d1[e-E0];     pos = pos1; noff = N0; }
  else               { s = s2[e-E0-E1];  d = d2[e-E0-E1];  pos = pos2; noff = N0+N1; }
  float dx = pos[d*3+0]-pos[s*3+0];
  float dy = pos[d*3+1]-pos[s*3+1];
  float dz = pos[d*3+2]-pos[s*3+2];
  int p = atomicAdd(&cur[noff + d], 1);
  srcs[p] = s;
  meta[p] = make_float4(sqrtf(dx*dx+dy*dy+dz*dz+1e-12f), dx, dy, dz);
}

// ---------------- transform: q, packed-kv (bf16), skip (Cout=32) ----------------
__global__ __launch_bounds__(256) void k_transform(
    const float* __restrict__ x,
    const float* __restrict__ Wq, const float* __restrict__ Wk,
    const float* __restrict__ Wv, const float* __restrict__ Ws,
    float* __restrict__ q, unsigned* __restrict__ kv, float* __restrict__ s,
    int n, int Cin){
  __shared__ float w4[4][1024];
  __shared__ float xr[8][96];
  __shared__ float kvst[8][192];
  int tid = threadIdx.x;
  int nw = Cin * 32;
  for (int i = tid; i < nw; i += 256){
    w4[0][i] = Wq[i]; w4[1][i] = Wk[i]; w4[2][i] = Wv[i]; w4[3][i] = Ws[i];
  }
  int g = tid >> 5, lane = tid & 31;
  int node = blockIdx.x*8 + g;
  int xl = Cin * 3;
  if (node < n){
    for (int j = lane; j < xl; j += 32) xr[g][j] = x[node*xl + j];
  }
  __syncthreads();
  if (node < n){
    #pragma unroll
    for (int vv = 0; vv < 3; ++vv){
      float aq=0.f, ak=0.f, av=0.f, as=0.f;
      for (int c = 0; c < Cin; ++c){
        float xv = xr[g][c*3+vv];
        aq += xv * w4[0][c*32+lane];
        ak += xv * w4[1][c*32+lane];
        av += xv * w4[2][c*32+lane];
        as += xv * w4[3][c*32+lane];
      }
      int o = node*96 + lane*3 + vv;
      q[o]=aq; s[o]=as;
      kvst[g][lane*3+vv] = ak;
      kvst[g][96 + lane*3+vv] = av;
    }
    #pragma unroll
    for (int t = 0; t < 3; ++t){
      int j = lane + 32*t;
      kv[node*96 + j] = bfpack(kvst[g][2*j], kvst[g][2*j+1]);
    }
  }
}

// ---------------- attention core macro-body (R5-proven 4-wide loop) ----------------
// computes y0,y1,y2 per lane (=channel) into named vars; needs vsum LDS.
#define ATTN_CORE(QB,KVB,SB) \
  float rw1 = (lane < 16) ? wr1[lane] : 0.f; \
  float rw2 = (lane < 16) ? wr2[lane] : 0.f; \
  float ql0=0.f, ql1=0.f, ql2=0.f, ql3=0.f; \
  float z=0.f, av0=0.f, av1=0.f, av2=0.f, av3=0.f, R0=0.f, R1=0.f, R2=0.f; \
  int beg=0, end=0; \
  if (act){ \
    int nb = node*96; \
    ql0 = QB[nb + 2*lane]*invsc;  ql1 = QB[nb + 2*lane+1]*invsc; \
    if (lane < 16){ ql2 = QB[nb + 64 + 2*lane]*invsc; ql3 = QB[nb + 65 + 2*lane]*invsc; } \
    beg = row[node]; end = row[node+1]; \
  } \
  for (int cb = beg; cb < end; cb += 32){ \
    int csz = end - cb; if (csz > 32) csz = 32; \
    int sn_l = 0; float4 mt = make_float4(0.f,0.f,0.f,0.f); \
    if (lane < csz){ \
      int idx = cb + lane; \
      sn_l = srcs[idx]; \
      mt = meta[idx]; \
    } \
    for (int j = 0; j < csz; j += 4){ \
      int gs = csz - j; if (gs > 4) gs = 4; \
      int sid[4]; float rrB[4]; \
      _Pragma("unroll") \
      for (int t = 0; t < 4; ++t){ \
        int sl = (j + t) & 31; \
        sid[t] = __shfl(sn_l, sl, 32); \
        rrB[t] = __shfl(mt.x, sl, 32); \
      } \
      unsigned d0[4], d1[4], d2[4]; \
      _Pragma("unroll") \
      for (int t = 0; t < 4; ++t){ \
        const unsigned* kp = KVB + (size_t)sid[t]*96; \
        bool ok = t < gs; \
        d0[t] = ok ? kp[lane]    : 0u; \
        d1[t] = ok ? kp[lane+32] : 0u; \
        d2[t] = ok ? kp[lane+64] : 0u; \
      } \
      _Pragma("unroll") \
      for (int t = 0; t < 4; ++t){ \
        float pt = bf_lo(d0[t])*ql0 + bf_hi(d0[t])*ql1; \
        if (lane < 16) pt += bf_lo(d1[t])*ql2 + bf_hi(d1[t])*ql3; \
        pt += fmaxf(rrB[t]*rw1, 0.f) * rw2; \
        _Pragma("unroll") \
        for (int off = 16; off; off >>= 1) pt += __shfl_xor(pt, off, 32); \
        float w = (t < gs) ? __expf(fminf(pt, 80.f)) : 0.f; \
        z += w; \
        av0 += w*bf_lo(d2[t]); av1 += w*bf_hi(d2[t]); \
        if (lane >= 16){ av2 += w*bf_lo(d1[t]); av3 += w*bf_hi(d1[t]); } \
        if (lane == j + t){ R0 += w*mt.y; R1 += w*mt.z; R2 += w*mt.w; } \
      } \
    } \
  } \
  _Pragma("unroll") \
  for (int off = 16; off; off >>= 1){ \
    R0 += __shfl_xor(R0, off, 32); \
    R1 += __shfl_xor(R1, off, 32); \
    R2 += __shfl_xor(R2, off, 32); \
  } \
  if (act){ \
    vsum[g][2*lane+32] = av0; \
    vsum[g][2*lane+33] = av1; \
    if (lane >= 16){ vsum[g][2*lane-32] = av2; vsum[g][2*lane-31] = av3; } \
  } \
  float y0=0.f, y1=0.f, y2=0.f; \
  if (act){ \
    float invz = 1.f / (z + EPS); \
    int base = node*96 + 3*lane; \
    y0 = (vsum[g][3*lane+0] + R0)*invz + SB[base]; \
    y1 = (vsum[g][3*lane+1] + R1)*invz + SB[base+1]; \
    y2 = (vsum[g][3*lane+2] + R2)*invz + SB[base+2]; \
    float nrm = sqrtf(y0*y0 + y1*y1 + y2*y2 + 1e-12f); \
    float f = fmaxf(scaleA[lane]*nrm + biasA[lane], 0.f) / nrm; \
    y0 *= f; y1 *= f; y2 *= f; \
  }

// ---------------- plain attention (odd layers): writes y ----------------
__global__ __launch_bounds__(256) void k_attn32(
    const float* __restrict__ qb, const unsigned* __restrict__ kvb,
    const float* __restrict__ sb,
    const int* __restrict__ row, const int* __restrict__ srcs,
    const float4* __restrict__ meta,
    const float* __restrict__ wr1, const float* __restrict__ wr2,
    const float* __restrict__ scaleA, const float* __restrict__ biasA,
    float* __restrict__ outb, int n, float invsc){
  __shared__ float vsum[8][96];
  int tid = threadIdx.x, g = tid >> 5, lane = tid & 31;
  int node = blockIdx.x*8 + g;
  bool act = node < n;
  ATTN_CORE(qb, kvb, sb)
  if (act){
    int base = node*96 + 3*lane;
    outb[base]   = y0;
    outb[base+1] = y1;
    outb[base+2] = y2;
  }
}

// ---------------- fused attention + next-layer transform (Cout=32) ----------------
// reads qb/sb (layer i), kvin; writes qb/sb IN-PLACE (layer i+1) and kvout.
__global__ __launch_bounds__(256) void k_attn32_t32(
    float* __restrict__ qb, const unsigned* __restrict__ kvin,
    float* __restrict__ sb,
    const int* __restrict__ row, const int* __restrict__ srcs,
    const float4* __restrict__ meta,
    const float* __restrict__ wr1, const float* __restrict__ wr2,
    const float* __restrict__ scaleA, const float* __restrict__ biasA,
    const float* __restrict__ Wq2, const float* __restrict__ Wk2,
    const float* __restrict__ Wv2, const float* __restrict__ Ws2,
    unsigned* __restrict__ kvout, int n, float invsc){
  __shared__ float vsum[8][96];
  __shared__ float w4[4][1024];
  __shared__ float kvst[8][192];
  int tid = threadIdx.x, g = tid >> 5, lane = tid & 31;
  for (int i = tid; i < 1024; i += 256){
    w4[0][i] = Wq2[i]; w4[1][i] = Wk2[i]; w4[2][i] = Wv2[i]; w4[3][i] = Ws2[i];
  }
  int node = blockIdx.x*8 + g;
  bool act = node < n;
  ATTN_CORE(qb, kvin, sb)
  __syncthreads();     // w4 staged by all waves; also orders vsum reuse
  if (act){
    // share y across the wave via vsum (in-place overwrite of own slots)
    vsum[g][3*lane+0] = y0;
    vsum[g][3*lane+1] = y1;
    vsum[g][3*lane+2] = y2;
    float aq0=0.f,aq1=0.f,aq2=0.f, ak0=0.f,ak1=0.f,ak2=0.f;
    float aw0=0.f,aw1=0.f,aw2=0.f, as0=0.f,as1=0.f,as2=0.f;
    for (int c = 0; c < 32; ++c){
      float x0 = vsum[g][c*3+0], x1 = vsum[g][c*3+1], x2 = vsum[g][c*3+2];
      float wq = w4[0][c*32+lane], wk = w4[1][c*32+lane];
      float wv = w4[2][c*32+lane], wsk = w4[3][c*32+lane];
      aq0 += x0*wq;  aq1 += x1*wq;  aq2 += x2*wq;
      ak0 += x0*wk;  ak1 += x1*wk;  ak2 += x2*wk;
      aw0 += x0*wv;  aw1 += x1*wv;  aw2 += x2*wv;
      as0 += x0*wsk; as1 += x1*wsk; as2 += x2*wsk;
    }
    int ob = node*96 + 3*lane;
    qb[ob]=aq0; qb[ob+1]=aq1; qb[ob+2]=aq2;
    sb[ob]=as0; sb[ob+1]=as1; sb[ob+2]=as2;
    kvst[g][lane*3+0]=ak0; kvst[g][lane*3+1]=ak1; kvst[g][lane*3+2]=ak2;
    kvst[g][96+lane*3+0]=aw0; kvst[g][96+lane*3+1]=aw1; kvst[g][96+lane*3+2]=aw2;
    #pragma unroll
    for (int t = 0; t < 3; ++t){
      int j = lane + 32*t;
      kvout[node*96 + j] = bfpack(kvst[g][2*j], kvst[g][2*j+1]);
    }
  }
}

// ---------------- fused attention + Cout=1 transform (pair 8,9) ----------------
__global__ __launch_bounds__(256) void k_attn32_t1(
    const float* __restrict__ qb, const unsigned* __restrict__ kvin,
    const float* __restrict__ sb,
    const int* __restrict__ row, const int* __restrict__ srcs,
    const float4* __restrict__ meta,
    const float* __restrict__ wr1, const float* __restrict__ wr2,
    const float* __restrict__ scaleA, const float* __restrict__ biasA,
    const float* __restrict__ Wq2, const float* __restrict__ Wk2,
    const float* __restrict__ Wv2, const float* __restrict__ Ws2,
    float* __restrict__ q1, float* __restrict__ k1,
    float* __restrict__ v1, float* __restrict__ s1,
    int n, float invsc){
  __shared__ float vsum[8][96];
  int tid = threadIdx.x, g = tid >> 5, lane = tid & 31;
  int node = blockIdx.x*8 + g;
  bool act = node < n;
  ATTN_CORE(qb, kvin, sb)
  if (act){
    vsum[g][3*lane+0] = y0;
    vsum[g][3*lane+1] = y1;
    vsum[g][3*lane+2] = y2;
  }
  // within-wave LDS visibility; lanes 0..11 compute the 12 outputs
  if (act && lane < 12){
    int m = lane / 3, v = lane - m*3;
    const float* W = (m==0) ? Wq2 : (m==1) ? Wk2 : (m==2) ? Wv2 : Ws2;
    float a = 0.f;
    for (int c = 0; c < 32; ++c) a += vsum[g][c*3+v] * W[c];
    float* out = (m==0) ? q1 : (m==1) ? k1 : (m==2) ? v1 : s1;
    out[node*3 + v] = a;
  }
}

// ---------------- Cout=1 attention fused with MLP head ----------------
__global__ __launch_bounds__(256) void k_attn1_head(
    const float* __restrict__ qb, const float* __restrict__ kb,
    const float* __restrict__ vb, const float* __restrict__ sb,
    const int* __restrict__ row, const int* __restrict__ srcs,
    const float4* __restrict__ meta,
    const float* __restrict__ wr1, const float* __restrict__ wr2,
    const float* __restrict__ scaleA, const float* __restrict__ biasA,
    const float* __restrict__ Wmlp,
    float* __restrict__ out, int n, float invsc){
  __shared__ float w[120];
  int tid = threadIdx.x;
  if (tid < 120) w[tid] = Wmlp[tid];
  __syncthreads();
  int i = blockIdx.x*256 + tid;
  if (i >= n) return;
  float q0 = qb[i*3]*invsc, q1 = qb[i*3+1]*invsc, q2 = qb[i*3+2]*invsc;
  float z = 0.f, a0 = 0.f, a1 = 0.f, a2 = 0.f;
  int beg = row[i], end = row[i+1];
  for (int e = beg; e < end; ++e){
    int s = srcs[e];
    float4 m = meta[e];
    float k0 = kb[s*3], k1 = kb[s*3+1], k2 = kb[s*3+2];
    float v0 = vb[s*3], v1 = vb[s*3+1], v2 = vb[s*3+2];
    float pt = q0*k0 + q1*k1 + q2*k2;
    float rb = 0.f;
    #pragma unroll
    for (int jr = 0; jr < 16; ++jr) rb += fmaxf(m.x*wr1[jr], 0.f)*wr2[jr];
    pt += rb;
    float wgt = __expf(fminf(pt, 80.f));
    z += wgt;
    a0 += wgt*(v0 + m.y); a1 += wgt*(v1 + m.z); a2 += wgt*(v2 + m.w);
  }
  float invz = 1.f / (z + EPS);
  float y0 = a0*invz + sb[i*3];
  float y1 = a1*invz + sb[i*3+1];
  float y2 = a2*invz + sb[i*3+2];
  float nrm = sqrtf(y0*y0 + y1*y1 + y2*y2 + 1e-12f);
  float f = fmaxf(scaleA[0]*nrm + biasA[0], 0.f) / nrm;
  y0 *= f; y1 *= f; y2 *= f;
  #pragma unroll
  for (int o2 = 0; o2 < 40; ++o2){
    out[(size_t)i*40 + o2] = fmaxf(y0*w[o2] + y1*w[40+o2] + y2*w[80+o2], 0.f);
  }
}

// ---------------- pooling ----------------
__global__ void k_pool_add(const float* __restrict__ x, const int* __restrict__ cl,
                           float* sum, float* cnt, int n0){
  int t = blockIdx.x*256 + threadIdx.x;
  if (t < n0*96){
    int nn = t / 96, j = t - nn*96;
    int c = cl[nn];
    atomicAdd(&sum[c*96 + j], x[t]);
    if (j == 0) atomicAdd(&cnt[c], 1.f);
  }
}
__global__ void k_pool_div(const float* __restrict__ sum, const float* __restrict__ cnt,
                           float* __restrict__ out, int n1){
  int t = blockIdx.x*256 + threadIdx.x;
  if (t < n1*96) out[t] = sum[t] / (cnt[t/96] + EPS);
}

extern "C" void kernel_launch(void* const* d_in, const int* in_sizes, int n_in,
                              void* d_out, int out_size, void* d_ws, size_t ws_size,
                              hipStream_t stream){
  const float* pos0      = (const float*)d_in[0];
  const float* v0        = (const float*)d_in[1];
  const float* Wq_first  = (const float*)d_in[2];
  const float* Wk_first  = (const float*)d_in[3];
  const float* Wv_first  = (const float*)d_in[4];
  const float* Ws_first  = (const float*)d_in[5];
  const float* Wq_mid    = (const float*)d_in[6];
  const float* Wk_mid    = (const float*)d_in[7];
  const float* Wv_mid    = (const float*)d_in[8];
  const float* Ws_mid    = (const float*)d_in[9];
  const float* Wq_last   = (const float*)d_in[10];
  const float* Wk_last   = (const float*)d_in[11];
  const float* Wv_last   = (const float*)d_in[12];
  const float* Ws_last   = (const float*)d_in[13];
  const float* wr1       = (const float*)d_in[14];
  const float* wr2       = (const float*)d_in[15];
  const float* scale_mid = (const float*)d_in[16];
  const float* bias_mid  = (const float*)d_in[17];
  const float* scale_last= (const float*)d_in[18];
  const float* bias_last = (const float*)d_in[19];
  const float* Wmlp      = (const float*)d_in[20];
  const int* src0 = (const int*)d_in[21];
  const int* dst0 = (const int*)d_in[22];
  const int* src1 = (const int*)d_in[23];
  const int* dst1 = (const int*)d_in[24];
  const int* src2 = (const int*)d_in[25];
  const int* dst2 = (const int*)d_in[26];
  const int* fp1  = (const int*)d_in[27];
  const int* fp2  = (const int*)d_in[28];
  const int* cl1  = (const int*)d_in[29];
  const int* cl2  = (const int*)d_in[30];

  float* ws = (float*)d_ws;
  size_t o = 0;
  float* xA   = ws + o; o += (size_t)N0*96;
  float* xB   = ws + o; o += (size_t)N0*96;
  float* x0s  = ws + o; o += (size_t)N0*96;
  float* x1s  = ws + o; o += (size_t)N1*96;
  float* qb   = ws + o; o += (size_t)N0*96;
  float* sb   = ws + o; o += (size_t)N0*96;
  unsigned* kvb  = (unsigned*)(ws + o); o += (size_t)N0*96;
  unsigned* kvb2 = (unsigned*)(ws + o); o += (size_t)N0*96;
  float4* metaA = (float4*)(ws + o); o += (size_t)ETOT*4;
  float* q1v  = ws + o; o += (size_t)N0*3;
  float* k1v  = ws + o; o += (size_t)N0*3;
  float* v1v  = ws + o; o += (size_t)N0*3;
  float* s1v  = ws + o; o += (size_t)N0*3;
  float* pcnt = ws + o; o += N1;
  float* pos1 = ws + o; o += (size_t)N1*3;
  float* pos2 = ws + o; o += (size_t)N2*3;
  int* ib = (int*)(ws + o);
  size_t io = 0;
  int* rowA  = ib + io; io += NTOT+1;
  int* cntA  = ib + io; io += NTOT;
  int* curA  = ib + io; io += NTOT;
  int* exclA = ib + io; io += NTOT;
  int* bsumA = ib + io; io += 256;
  int* srcsA = ib + io; io += ETOT;
  int* inv0  = ib + io; io += N0;
  int* inv1  = ib + io; io += N1;

  k_gather_pos<<<cdiv(N1,256),256,0,stream>>>(pos0, fp1, pos1, N1);
  k_gather_pos<<<cdiv(N2,256),256,0,stream>>>(pos1, fp2, pos2, N2);

  hipMemsetAsync(inv0, 0xFF, N0*sizeof(int), stream);
  hipMemsetAsync(inv1, 0xFF, N1*sizeof(int), stream);
  k_inv_build<<<cdiv(N1,256),256,0,stream>>>(fp1, inv0, N1);
  k_inv_build<<<cdiv(N2,256),256,0,stream>>>(fp2, inv1, N2);

  hipMemsetAsync(cntA, 0, NTOT*sizeof(int), stream);
  k_countA<<<cdiv(ETOT,256),256,0,stream>>>(dst0, dst1, dst2, cntA);
  k_scan1<<<NBLK,256,0,stream>>>(cntA, exclA, bsumA);
  k_scan2<<<1,256,0,stream>>>(bsumA, NBLK);
  k_scan3<<<NBLK,256,0,stream>>>(exclA, bsumA, rowA, curA);
  k_scatter_geoA<<<cdiv(ETOT,256),256,0,stream>>>(src0, dst0, src1, dst1, src2, dst2,
                                                  pos0, pos1, pos2, curA, srcsA, metaA);

  const float invsc = 1.f / sqrtf(96.f);
  const int C = 32;

  // fused pair driver: T_even, attn_even+T_odd, attn_odd
  auto pair32 = [&](const float* xin, int n, int nodeBase, int Cin,
                    const float* WqE, const float* WkE, const float* WvE, const float* WsE,
                    const float* WqO, const float* WkO, const float* WvO, const float* WsO,
                    int lE, float* xout){
    k_transform<<<cdiv(n,8),256,0,stream>>>(xin, WqE, WkE, WvE, WsE, qb, kvb, sb, n, Cin);
    k_attn32_t32<<<cdiv(n,8),256,0,stream>>>(qb, kvb, sb, rowA + nodeBase, srcsA, metaA,
                                             wr1 + lE*16, wr2 + lE*16,
                                             scale_mid + lE*C, bias_mid + lE*C,
                                             WqO, WkO, WvO, WsO, kvb2, n, invsc);
    k_attn32<<<cdiv(n,8),256,0,stream>>>(qb, kvb2, sb, rowA + nodeBase, srcsA, metaA,
                                         wr1 + (lE+1)*16, wr2 + (lE+1)*16,
                                         scale_mid + (lE+1)*C, bias_mid + (lE+1)*C,
                                         xout, n, invsc);
  };

  // pair (0,1) at level 0 -> x0s
  pair32(v0, N0, 0, 1,
         Wq_first, Wk_first, Wv_first, Ws_first,
         Wq_mid+0*1024, Wk_mid+0*1024, Wv_mid+0*1024, Ws_mid+0*1024,
         0, x0s);
  // pool -> level 1
  hipMemsetAsync(xA, 0, (size_t)N1*96*sizeof(float), stream);
  hipMemsetAsync(pcnt, 0, N1*sizeof(float), stream);
  k_pool_add<<<cdiv(N0*96,256),256,0,stream>>>(x0s, cl1, xA, pcnt, N0);
  k_pool_div<<<cdiv(N1*96,256),256,0,stream>>>(xA, pcnt, xB, N1);
  // pair (2,3) at level 1 -> x1s
  pair32(xB, N1, N0, C,
         Wq_mid+1*1024, Wk_mid+1*1024, Wv_mid+1*1024, Ws_mid+1*1024,
         Wq_mid+2*1024, Wk_mid+2*1024, Wv_mid+2*1024, Ws_mid+2*1024,
         2, x1s);
  // pool -> level 2
  hipMemsetAsync(xA, 0, (size_t)N2*96*sizeof(float), stream);
  hipMemsetAsync(pcnt, 0, N2*sizeof(float), stream);
  k_pool_add<<<cdiv(N1*96,256),256,0,stream>>>(x1s, cl2, xA, pcnt, N1);
  k_pool_div<<<cdiv(N2*96,256),256,0,stream>>>(xA, pcnt, xB, N2);
  // pair (4,5) at level 2 -> xA (N2 rows)
  pair32(xB, N2, N0+N1, C,
         Wq_mid+3*1024, Wk_mid+3*1024, Wv_mid+3*1024, Ws_mid+3*1024,
         Wq_mid+4*1024, Wk_mid+4*1024, Wv_mid+4*1024, Ws_mid+4*1024,
         4, xA);
  // upsample level2 -> level1 : xB = x1s + scatter(xA)
  k_upsample<<<cdiv(N1*96,256),256,0,stream>>>(x1s, xA, inv1, xB, N1);
  // pair (6,7) at level 1 -> xA (N1 rows)
  pair32(xB, N1, N0, C,
         Wq_mid+5*1024, Wk_mid+5*1024, Wv_mid+5*1024, Ws_mid+5*1024,
         Wq_mid+6*1024, Wk_mid+6*1024, Wv_mid+6*1024, Ws_mid+6*1024,
         6, xA);
  // upsample level1 -> level0 : xB = x0s + scatter(xA)
  k_upsample<<<cdiv(N0*96,256),256,0,stream>>>(x0s, xA, inv0, xB, N0);
  // pair (8,9): T8, attn8 + T9(Cout=1), attn9+head
  k_transform<<<cdiv(N0,8),256,0,stream>>>(xB, Wq_mid+7*1024, Wk_mid+7*1024,
                                           Wv_mid+7*1024, Ws_mid+7*1024,
                                           qb, kvb, sb, N0, C);
  k_attn32_t1<<<cdiv(N0,8),256,0,stream>>>(qb, kvb, sb, rowA, srcsA, metaA,
                                           wr1 + 8*16, wr2 + 8*16,
                                           scale_mid + 8*C, bias_mid + 8*C,
                                           Wq_last, Wk_last, Wv_last, Ws_last,
                                           q1v, k1v, v1v, s1v, N0, invsc);
  {
    float invsc1 = 1.f / sqrtf(3.f);
    k_attn1_head<<<cdiv(N0,256),256,0,stream>>>(q1v, k1v, v1v, s1v, rowA, srcsA, metaA,
                                                wr1 + 9*16, wr2 + 9*16,
                                                scale_last, bias_last,
                                                Wmlp, (float*)d_out, N0, invsc1);
  }
}

// Round 9
// 500.557 us; speedup vs baseline: 1.2081x; 1.0128x over previous
//
#include <hip/hip_runtime.h>
#include <math.h>

#define N0 32768
#define N1 8192
#define N2 2048
#define E0 262144
#define E1 65536
#define E2 16384
#define NTOT (N0+N1+N2)     // 43008
#define ETOT (E0+E1+E2)     // 344064
#define NBLK (NTOT/256)     // 168
#define EPS 1e-9f

static inline int cdiv(int a, int b){ return (a + b - 1) / b; }

__device__ inline unsigned bfpack(float a, float b){
  unsigned ua = __float_as_uint(a), ub = __float_as_uint(b);
  ua = (ua + 0x7fffu + ((ua >> 16) & 1u)) >> 16;
  ub = (ub + 0x7fffu + ((ub >> 16) & 1u)) & 0xffff0000u;
  return ua | ub;
}
__device__ inline float bf_lo(unsigned d){ return __uint_as_float(d << 16); }
__device__ inline float bf_hi(unsigned d){ return __uint_as_float(d & 0xffff0000u); }

// ---------------- small utility kernels ----------------
__global__ void k_gather_pos(const float* __restrict__ pos, const int* __restrict__ idx,
                             float* __restrict__ out, int n){
  int i = blockIdx.x*256 + threadIdx.x;
  if (i < n){
    int s = idx[i];
    out[i*3+0] = pos[s*3+0];
    out[i*3+1] = pos[s*3+1];
    out[i*3+2] = pos[s*3+2];
  }
}
__global__ void k_inv_build(const int* __restrict__ fp, int* __restrict__ inv, int n2){
  int i = blockIdx.x*256 + threadIdx.x;
  if (i < n2) inv[fp[i]] = i;
}

// ---------------- concatenated CSR build ----------------
__global__ void k_countA(const int* __restrict__ d0, const int* __restrict__ d1,
                         const int* __restrict__ d2, int* cnt){
  int e = blockIdx.x*256 + threadIdx.x;
  if (e < E0)            atomicAdd(&cnt[d0[e]], 1);
  else if (e < E0+E1)    atomicAdd(&cnt[N0 + d1[e-E0]], 1);
  else if (e < ETOT)     atomicAdd(&cnt[N0+N1 + d2[e-E0-E1]], 1);
}
__global__ __launch_bounds__(256) void k_scan1(const int* __restrict__ cnt,
                                               int* __restrict__ excl,
                                               int* __restrict__ bsum){
  __shared__ int lds[256];
  int tid = threadIdx.x;
  int i = blockIdx.x*256 + tid;
  int v = cnt[i];
  lds[tid] = v;
  __syncthreads();
  for (int off = 1; off < 256; off <<= 1){
    int t = (tid >= off) ? lds[tid - off] : 0;
    __syncthreads();
    lds[tid] += t;
    __syncthreads();
  }
  excl[i] = lds[tid] - v;
  if (tid == 255) bsum[blockIdx.x] = lds[255];
}
__global__ __launch_bounds__(256) void k_scan2(int* bsum, int nb){
  __shared__ int lds[256];
  int tid = threadIdx.x;
  int v = (tid < nb) ? bsum[tid] : 0;
  lds[tid] = v;
  __syncthreads();
  for (int off = 1; off < 256; off <<= 1){
    int t = (tid >= off) ? lds[tid - off] : 0;
    __syncthreads();
    lds[tid] += t;
    __syncthreads();
  }
  if (tid < nb) bsum[tid] = lds[tid] - v;
}
__global__ __launch_bounds__(256) void k_scan3(const int* __restrict__ excl,
                                               const int* __restrict__ bsum,
                                               int* __restrict__ row,
                                               int* __restrict__ cur){
  int i = blockIdx.x*256 + threadIdx.x;
  int r = excl[i] + bsum[blockIdx.x];
  row[i] = r; cur[i] = r;
  if (i == 0) row[NTOT] = ETOT;
}
__global__ void k_scatter_geoA(const int* __restrict__ s0, const int* __restrict__ d0,
                               const int* __restrict__ s1, const int* __restrict__ d1,
                               const int* __restrict__ s2, const int* __restrict__ d2,
                               const float* __restrict__ pos0, const float* __restrict__ pos1,
                               const float* __restrict__ pos2, int* cur,
                               int* __restrict__ srcs, float4* __restrict__ meta){
  int e = blockIdx.x*256 + threadIdx.x;
  if (e >= ETOT) return;
  int s, d, noff; const float* pos;
  if (e < E0)        { s = s0[e];        d = d0[e];        pos = pos0; noff = 0; }
  else if (e < E0+E1){ s = s1[e-E0];     d = d1[e-E0];     pos = pos1; noff = N0; }
  else               { s = s2[e-E0-E1];  d = d2[e-E0-E1];  pos = pos2; noff = N0+N1; }
  float dx = pos[d*3+0]-pos[s*3+0];
  float dy = pos[d*3+1]-pos[s*3+1];
  float dz = pos[d*3+2]-pos[s*3+2];
  int p = atomicAdd(&cur[noff + d], 1);
  srcs[p] = s;
  meta[p] = make_float4(sqrtf(dx*dx+dy*dy+dz*dz+1e-12f), dx, dy, dz);
}

// ---------------- transform: q, packed-kv (bf16), skip (Cout=32) ----------------
// mode 0: x plain | mode 1: POOL x=sum/(cnt+EPS) | mode 2: UPS x=base+up[inv]
__global__ __launch_bounds__(256) void k_transformF(
    const float* __restrict__ x, const float* __restrict__ cntv,
    const float* __restrict__ up, const int* __restrict__ inv,
    const float* __restrict__ Wq, const float* __restrict__ Wk,
    const float* __restrict__ Wv, const float* __restrict__ Ws,
    float* __restrict__ q, unsigned* __restrict__ kv, float* __restrict__ s,
    int n, int Cin, int mode){
  __shared__ float w4[4][1024];
  __shared__ float xr[8][96];
  __shared__ float kvst[8][192];
  int tid = threadIdx.x;
  int nw = Cin * 32;
  for (int i = tid; i < nw; i += 256){
    w4[0][i] = Wq[i]; w4[1][i] = Wk[i]; w4[2][i] = Wv[i]; w4[3][i] = Ws[i];
  }
  int g = tid >> 5, lane = tid & 31;
  int node = blockIdx.x*8 + g;
  int xl = Cin * 3;
  if (node < n){
    if (mode == 1){
      float ic = 1.f / (cntv[node] + EPS);
      for (int j = lane; j < xl; j += 32) xr[g][j] = x[node*xl + j] * ic;
    } else if (mode == 2){
      int a = inv[node];
      for (int j = lane; j < xl; j += 32){
        float v = x[node*xl + j];
        if (a >= 0) v += up[(size_t)a*xl + j];
        xr[g][j] = v;
      }
    } else {
      for (int j = lane; j < xl; j += 32) xr[g][j] = x[node*xl + j];
    }
  }
  __syncthreads();
  if (node < n){
    #pragma unroll
    for (int vv = 0; vv < 3; ++vv){
      float aq=0.f, ak=0.f, av=0.f, as=0.f;
      for (int c = 0; c < Cin; ++c){
        float xv = xr[g][c*3+vv];
        aq += xv * w4[0][c*32+lane];
        ak += xv * w4[1][c*32+lane];
        av += xv * w4[2][c*32+lane];
        as += xv * w4[3][c*32+lane];
      }
      int o = node*96 + lane*3 + vv;
      q[o]=aq; s[o]=as;
      kvst[g][lane*3+vv] = ak;
      kvst[g][96 + lane*3+vv] = av;
    }
    #pragma unroll
    for (int t = 0; t < 3; ++t){
      int j = lane + 32*t;
      kv[node*96 + j] = bfpack(kvst[g][2*j], kvst[g][2*j+1]);
    }
  }
}

// ---------------- attention core (R5-proven 4-wide loop) ----------------
#define ATTN_CORE(QB,KVB,SB) \
  float rw1 = (lane < 16) ? wr1[lane] : 0.f; \
  float rw2 = (lane < 16) ? wr2[lane] : 0.f; \
  float ql0=0.f, ql1=0.f, ql2=0.f, ql3=0.f; \
  float z=0.f, av0=0.f, av1=0.f, av2=0.f, av3=0.f, R0=0.f, R1=0.f, R2=0.f; \
  int beg=0, end=0; \
  if (act){ \
    int nb = node*96; \
    ql0 = QB[nb + 2*lane]*invsc;  ql1 = QB[nb + 2*lane+1]*invsc; \
    if (lane < 16){ ql2 = QB[nb + 64 + 2*lane]*invsc; ql3 = QB[nb + 65 + 2*lane]*invsc; } \
    beg = row[node]; end = row[node+1]; \
  } \
  for (int cb = beg; cb < end; cb += 32){ \
    int csz = end - cb; if (csz > 32) csz = 32; \
    int sn_l = 0; float4 mt = make_float4(0.f,0.f,0.f,0.f); \
    if (lane < csz){ \
      int idx = cb + lane; \
      sn_l = srcs[idx]; \
      mt = meta[idx]; \
    } \
    for (int j = 0; j < csz; j += 4){ \
      int gs = csz - j; if (gs > 4) gs = 4; \
      int sid[4]; float rrB[4]; \
      _Pragma("unroll") \
      for (int t = 0; t < 4; ++t){ \
        int sl = (j + t) & 31; \
        sid[t] = __shfl(sn_l, sl, 32); \
        rrB[t] = __shfl(mt.x, sl, 32); \
      } \
      unsigned d0[4], d1[4], d2[4]; \
      _Pragma("unroll") \
      for (int t = 0; t < 4; ++t){ \
        const unsigned* kp = KVB + (size_t)sid[t]*96; \
        bool ok = t < gs; \
        d0[t] = ok ? kp[lane]    : 0u; \
        d1[t] = ok ? kp[lane+32] : 0u; \
        d2[t] = ok ? kp[lane+64] : 0u; \
      } \
      _Pragma("unroll") \
      for (int t = 0; t < 4; ++t){ \
        float pt = bf_lo(d0[t])*ql0 + bf_hi(d0[t])*ql1; \
        if (lane < 16) pt += bf_lo(d1[t])*ql2 + bf_hi(d1[t])*ql3; \
        pt += fmaxf(rrB[t]*rw1, 0.f) * rw2; \
        _Pragma("unroll") \
        for (int off = 16; off; off >>= 1) pt += __shfl_xor(pt, off, 32); \
        float w = (t < gs) ? __expf(fminf(pt, 80.f)) : 0.f; \
        z += w; \
        av0 += w*bf_lo(d2[t]); av1 += w*bf_hi(d2[t]); \
        if (lane >= 16){ av2 += w*bf_lo(d1[t]); av3 += w*bf_hi(d1[t]); } \
        if (lane == j + t){ R0 += w*mt.y; R1 += w*mt.z; R2 += w*mt.w; } \
      } \
    } \
  } \
  _Pragma("unroll") \
  for (int off = 16; off; off >>= 1){ \
    R0 += __shfl_xor(R0, off, 32); \
    R1 += __shfl_xor(R1, off, 32); \
    R2 += __shfl_xor(R2, off, 32); \
  } \
  if (act){ \
    vsum[g][2*lane+32] = av0; \
    vsum[g][2*lane+33] = av1; \
    if (lane >= 16){ vsum[g][2*lane-32] = av2; vsum[g][2*lane-31] = av3; } \
  } \
  float y0=0.f, y1=0.f, y2=0.f; \
  if (act){ \
    float invz = 1.f / (z + EPS); \
    int base = node*96 + 3*lane; \
    y0 = (vsum[g][3*lane+0] + R0)*invz + SB[base]; \
    y1 = (vsum[g][3*lane+1] + R1)*invz + SB[base+1]; \
    y2 = (vsum[g][3*lane+2] + R2)*invz + SB[base+2]; \
    float nrm = sqrtf(y0*y0 + y1*y1 + y2*y2 + 1e-12f); \
    float f = fmaxf(scaleA[lane]*nrm + biasA[lane], 0.f) / nrm; \
    y0 *= f; y1 *= f; y2 *= f; \
  }

// ---------------- plain attention (odd layers): writes y, optional fused pool ----------------
__global__ __launch_bounds__(256) void k_attn32(
    const float* __restrict__ qb, const unsigned* __restrict__ kvb,
    const float* __restrict__ sb,
    const int* __restrict__ row, const int* __restrict__ srcs,
    const float4* __restrict__ meta,
    const float* __restrict__ wr1, const float* __restrict__ wr2,
    const float* __restrict__ scaleA, const float* __restrict__ biasA,
    float* __restrict__ outb,
    float* psum, float* pcnt_, const int* __restrict__ cl,
    int n, float invsc){
  __shared__ float vsum[8][96];
  int tid = threadIdx.x, g = tid >> 5, lane = tid & 31;
  int node = blockIdx.x*8 + g;
  bool act = node < n;
  ATTN_CORE(qb, kvb, sb)
  if (act){
    int base = node*96 + 3*lane;
    outb[base]   = y0;
    outb[base+1] = y1;
    outb[base+2] = y2;
    if (cl){                        // fused segment-sum pooling
      int c = cl[node];
      atomicAdd(&psum[c*96 + 3*lane],   y0);
      atomicAdd(&psum[c*96 + 3*lane+1], y1);
      atomicAdd(&psum[c*96 + 3*lane+2], y2);
      if (lane == 0) atomicAdd(&pcnt_[c], 1.f);
    }
  }
}

// ---------------- fused attention + next-layer transform (Cout=32) ----------------
__global__ __launch_bounds__(256) void k_attn32_t32(
    float* __restrict__ qb, const unsigned* __restrict__ kvin,
    float* __restrict__ sb,
    const int* __restrict__ row, const int* __restrict__ srcs,
    const float4* __restrict__ meta,
    const float* __restrict__ wr1, const float* __restrict__ wr2,
    const float* __restrict__ scaleA, const float* __restrict__ biasA,
    const float* __restrict__ Wq2, const float* __restrict__ Wk2,
    const float* __restrict__ Wv2, const float* __restrict__ Ws2,
    unsigned* __restrict__ kvout, int n, float invsc){
  __shared__ float vsum[8][96];
  __shared__ float w4[4][1024];
  __shared__ float kvst[8][192];
  int tid = threadIdx.x, g = tid >> 5, lane = tid & 31;
  for (int i = tid; i < 1024; i += 256){
    w4[0][i] = Wq2[i]; w4[1][i] = Wk2[i]; w4[2][i] = Wv2[i]; w4[3][i] = Ws2[i];
  }
  int node = blockIdx.x*8 + g;
  bool act = node < n;
  ATTN_CORE(qb, kvin, sb)
  __syncthreads();
  if (act){
    vsum[g][3*lane+0] = y0;
    vsum[g][3*lane+1] = y1;
    vsum[g][3*lane+2] = y2;
    float aq0=0.f,aq1=0.f,aq2=0.f, ak0=0.f,ak1=0.f,ak2=0.f;
    float aw0=0.f,aw1=0.f,aw2=0.f, as0=0.f,as1=0.f,as2=0.f;
    for (int c = 0; c < 32; ++c){
      float x0 = vsum[g][c*3+0], x1 = vsum[g][c*3+1], x2 = vsum[g][c*3+2];
      float wq = w4[0][c*32+lane], wk = w4[1][c*32+lane];
      float wv = w4[2][c*32+lane], wsk = w4[3][c*32+lane];
      aq0 += x0*wq;  aq1 += x1*wq;  aq2 += x2*wq;
      ak0 += x0*wk;  ak1 += x1*wk;  ak2 += x2*wk;
      aw0 += x0*wv;  aw1 += x1*wv;  aw2 += x2*wv;
      as0 += x0*wsk; as1 += x1*wsk; as2 += x2*wsk;
    }
    int ob = node*96 + 3*lane;
    qb[ob]=aq0; qb[ob+1]=aq1; qb[ob+2]=aq2;
    sb[ob]=as0; sb[ob+1]=as1; sb[ob+2]=as2;
    kvst[g][lane*3+0]=ak0; kvst[g][lane*3+1]=ak1; kvst[g][lane*3+2]=ak2;
    kvst[g][96+lane*3+0]=aw0; kvst[g][96+lane*3+1]=aw1; kvst[g][96+lane*3+2]=aw2;
    #pragma unroll
    for (int t = 0; t < 3; ++t){
      int j = lane + 32*t;
      kvout[node*96 + j] = bfpack(kvst[g][2*j], kvst[g][2*j+1]);
    }
  }
}

// ---------------- fused attention + Cout=1 transform (pair 8,9) ----------------
__global__ __launch_bounds__(256) void k_attn32_t1(
    const float* __restrict__ qb, const unsigned* __restrict__ kvin,
    const float* __restrict__ sb,
    const int* __restrict__ row, const int* __restrict__ srcs,
    const float4* __restrict__ meta,
    const float* __restrict__ wr1, const float* __restrict__ wr2,
    const float* __restrict__ scaleA, const float* __restrict__ biasA,
    const float* __restrict__ Wq2, const float* __restrict__ Wk2,
    const float* __restrict__ Wv2, const float* __restrict__ Ws2,
    float* __restrict__ q1, float* __restrict__ k1,
    float* __restrict__ v1, float* __restrict__ s1,
    int n, float invsc){
  __shared__ float vsum[8][96];
  int tid = threadIdx.x, g = tid >> 5, lane = tid & 31;
  int node = blockIdx.x*8 + g;
  bool act = node < n;
  ATTN_CORE(qb, kvin, sb)
  if (act){
    vsum[g][3*lane+0] = y0;
    vsum[g][3*lane+1] = y1;
    vsum[g][3*lane+2] = y2;
  }
  if (act && lane < 12){
    int m = lane / 3, v = lane - m*3;
    const float* W = (m==0) ? Wq2 : (m==1) ? Wk2 : (m==2) ? Wv2 : Ws2;
    float a = 0.f;
    for (int c = 0; c < 32; ++c) a += vsum[g][c*3+v] * W[c];
    float* out = (m==0) ? q1 : (m==1) ? k1 : (m==2) ? v1 : s1;
    out[node*3 + v] = a;
  }
}

// ---------------- Cout=1 attention fused with MLP head ----------------
__global__ __launch_bounds__(256) void k_attn1_head(
    const float* __restrict__ qb, const float* __restrict__ kb,
    const float* __restrict__ vb, const float* __restrict__ sb,
    const int* __restrict__ row, const int* __restrict__ srcs,
    const float4* __restrict__ meta,
    const float* __restrict__ wr1, const float* __restrict__ wr2,
    const float* __restrict__ scaleA, const float* __restrict__ biasA,
    const float* __restrict__ Wmlp,
    float* __restrict__ out, int n, float invsc){
  __shared__ float w[120];
  int tid = threadIdx.x;
  if (tid < 120) w[tid] = Wmlp[tid];
  __syncthreads();
  int i = blockIdx.x*256 + tid;
  if (i >= n) return;
  float q0 = qb[i*3]*invsc, q1 = qb[i*3+1]*invsc, q2 = qb[i*3+2]*invsc;
  float z = 0.f, a0 = 0.f, a1 = 0.f, a2 = 0.f;
  int beg = row[i], end = row[i+1];
  for (int e = beg; e < end; ++e){
    int s = srcs[e];
    float4 m = meta[e];
    float k0 = kb[s*3], k1 = kb[s*3+1], k2 = kb[s*3+2];
    float v0 = vb[s*3], v1 = vb[s*3+1], v2 = vb[s*3+2];
    float pt = q0*k0 + q1*k1 + q2*k2;
    float rb = 0.f;
    #pragma unroll
    for (int jr = 0; jr < 16; ++jr) rb += fmaxf(m.x*wr1[jr], 0.f)*wr2[jr];
    pt += rb;
    float wgt = __expf(fminf(pt, 80.f));
    z += wgt;
    a0 += wgt*(v0 + m.y); a1 += wgt*(v1 + m.z); a2 += wgt*(v2 + m.w);
  }
  float invz = 1.f / (z + EPS);
  float y0 = a0*invz + sb[i*3];
  float y1 = a1*invz + sb[i*3+1];
  float y2 = a2*invz + sb[i*3+2];
  float nrm = sqrtf(y0*y0 + y1*y1 + y2*y2 + 1e-12f);
  float f = fmaxf(scaleA[0]*nrm + biasA[0], 0.f) / nrm;
  y0 *= f; y1 *= f; y2 *= f;
  #pragma unroll
  for (int o2 = 0; o2 < 40; ++o2){
    out[(size_t)i*40 + o2] = fmaxf(y0*w[o2] + y1*w[40+o2] + y2*w[80+o2], 0.f);
  }
}

extern "C" void kernel_launch(void* const* d_in, const int* in_sizes, int n_in,
                              void* d_out, int out_size, void* d_ws, size_t ws_size,
                              hipStream_t stream){
  const float* pos0      = (const float*)d_in[0];
  const float* v0        = (const float*)d_in[1];
  const float* Wq_first  = (const float*)d_in[2];
  const float* Wk_first  = (const float*)d_in[3];
  const float* Wv_first  = (const float*)d_in[4];
  const float* Ws_first  = (const float*)d_in[5];
  const float* Wq_mid    = (const float*)d_in[6];
  const float* Wk_mid    = (const float*)d_in[7];
  const float* Wv_mid    = (const float*)d_in[8];
  const float* Ws_mid    = (const float*)d_in[9];
  const float* Wq_last   = (const float*)d_in[10];
  const float* Wk_last   = (const float*)d_in[11];
  const float* Wv_last   = (const float*)d_in[12];
  const float* Ws_last   = (const float*)d_in[13];
  const float* wr1       = (const float*)d_in[14];
  const float* wr2       = (const float*)d_in[15];
  const float* scale_mid = (const float*)d_in[16];
  const float* bias_mid  = (const float*)d_in[17];
  const float* scale_last= (const float*)d_in[18];
  const float* bias_last = (const float*)d_in[19];
  const float* Wmlp      = (const float*)d_in[20];
  const int* src0 = (const int*)d_in[21];
  const int* dst0 = (const int*)d_in[22];
  const int* src1 = (const int*)d_in[23];
  const int* dst1 = (const int*)d_in[24];
  const int* src2 = (const int*)d_in[25];
  const int* dst2 = (const int*)d_in[26];
  const int* fp1  = (const int*)d_in[27];
  const int* fp2  = (const int*)d_in[28];
  const int* cl1  = (const int*)d_in[29];
  const int* cl2  = (const int*)d_in[30];

  float* ws = (float*)d_ws;
  size_t o = 0;
  float* xA   = ws + o; o += (size_t)N0*96;   // scratch fiber (attn5/attn7 outputs)
  float* x0s  = ws + o; o += (size_t)N0*96;   // level-0 skip
  float* x1s  = ws + o; o += (size_t)N1*96;   // level-1 skip
  float* xP1  = ws + o; o += (size_t)N1*96;   // pool-1 sums
  float* xP2  = ws + o; o += (size_t)N2*96;   // pool-2 sums
  float* qb   = ws + o; o += (size_t)N0*96;
  float* sb   = ws + o; o += (size_t)N0*96;
  unsigned* kvb  = (unsigned*)(ws + o); o += (size_t)N0*96;
  unsigned* kvb2 = (unsigned*)(ws + o); o += (size_t)N0*96;
  float4* metaA = (float4*)(ws + o); o += (size_t)ETOT*4;
  float* q1v  = ws + o; o += (size_t)N0*3;
  float* k1v  = ws + o; o += (size_t)N0*3;
  float* v1v  = ws + o; o += (size_t)N0*3;
  float* s1v  = ws + o; o += (size_t)N0*3;
  float* pcnt1 = ws + o; o += N1;
  float* pcnt2 = ws + o; o += N2;
  float* pos1 = ws + o; o += (size_t)N1*3;
  float* pos2 = ws + o; o += (size_t)N2*3;
  int* ib = (int*)(ws + o);
  size_t io = 0;
  int* rowA  = ib + io; io += NTOT+1;
  int* cntA  = ib + io; io += NTOT;
  int* curA  = ib + io; io += NTOT;
  int* exclA = ib + io; io += NTOT;
  int* bsumA = ib + io; io += 256;
  int* srcsA = ib + io; io += ETOT;
  int* inv0  = ib + io; io += N0;
  int* inv1  = ib + io; io += N1;

  // ---- zero pool accumulators up-front (graph-safe, before any attn writes) ----
  hipMemsetAsync(xP1, 0, (size_t)N1*96*sizeof(float), stream);
  hipMemsetAsync(xP2, 0, (size_t)N2*96*sizeof(float), stream);
  hipMemsetAsync(pcnt1, 0, N1*sizeof(float), stream);
  hipMemsetAsync(pcnt2, 0, N2*sizeof(float), stream);
  hipMemsetAsync(inv0, 0xFF, N0*sizeof(int), stream);
  hipMemsetAsync(inv1, 0xFF, N1*sizeof(int), stream);
  hipMemsetAsync(cntA, 0, NTOT*sizeof(int), stream);

  k_gather_pos<<<cdiv(N1,256),256,0,stream>>>(pos0, fp1, pos1, N1);
  k_gather_pos<<<cdiv(N2,256),256,0,stream>>>(pos1, fp2, pos2, N2);
  k_inv_build<<<cdiv(N1,256),256,0,stream>>>(fp1, inv0, N1);
  k_inv_build<<<cdiv(N2,256),256,0,stream>>>(fp2, inv1, N2);

  k_countA<<<cdiv(ETOT,256),256,0,stream>>>(dst0, dst1, dst2, cntA);
  k_scan1<<<NBLK,256,0,stream>>>(cntA, exclA, bsumA);
  k_scan2<<<1,256,0,stream>>>(bsumA, NBLK);
  k_scan3<<<NBLK,256,0,stream>>>(exclA, bsumA, rowA, curA);
  k_scatter_geoA<<<cdiv(ETOT,256),256,0,stream>>>(src0, dst0, src1, dst1, src2, dst2,
                                                  pos0, pos1, pos2, curA, srcsA, metaA);

  const float invsc = 1.f / sqrtf(96.f);
  const int C = 32;

  // pair driver: T_even(mode), attn_even+T_odd, attn_odd(+pool)
  auto pair32 = [&](const float* xin, const float* cntv, const float* up, const int* inv,
                    int mode, int n, int nodeBase, int Cin,
                    const float* WqE, const float* WkE, const float* WvE, const float* WsE,
                    const float* WqO, const float* WkO, const float* WvO, const float* WsO,
                    int lE, float* xout,
                    float* psum, float* pcnt_, const int* cl){
    k_transformF<<<cdiv(n,8),256,0,stream>>>(xin, cntv, up, inv, WqE, WkE, WvE, WsE,
                                             qb, kvb, sb, n, Cin, mode);
    k_attn32_t32<<<cdiv(n,8),256,0,stream>>>(qb, kvb, sb, rowA + nodeBase, srcsA, metaA,
                                             wr1 + lE*16, wr2 + lE*16,
                                             scale_mid + lE*C, bias_mid + lE*C,
                                             WqO, WkO, WvO, WsO, kvb2, n, invsc);
    k_attn32<<<cdiv(n,8),256,0,stream>>>(qb, kvb2, sb, rowA + nodeBase, srcsA, metaA,
                                         wr1 + (lE+1)*16, wr2 + (lE+1)*16,
                                         scale_mid + (lE+1)*C, bias_mid + (lE+1)*C,
                                         xout, psum, pcnt_, cl, n, invsc);
  };

  // pair (0,1) level 0 -> x0s, fused pool into xP1/pcnt1
  pair32(v0, nullptr, nullptr, nullptr, 0, N0, 0, 1,
         Wq_first, Wk_first, Wv_first, Ws_first,
         Wq_mid+0*1024, Wk_mid+0*1024, Wv_mid+0*1024, Ws_mid+0*1024,
         0, x0s, xP1, pcnt1, cl1);
  // pair (2,3) level 1 (POOL input) -> x1s, fused pool into xP2/pcnt2
  pair32(xP1, pcnt1, nullptr, nullptr, 1, N1, N0, C,
         Wq_mid+1*1024, Wk_mid+1*1024, Wv_mid+1*1024, Ws_mid+1*1024,
         Wq_mid+2*1024, Wk_mid+2*1024, Wv_mid+2*1024, Ws_mid+2*1024,
         2, x1s, xP2, pcnt2, cl2);
  // pair (4,5) level 2 (POOL input) -> xA (N2 rows)
  pair32(xP2, pcnt2, nullptr, nullptr, 1, N2, N0+N1, C,
         Wq_mid+3*1024, Wk_mid+3*1024, Wv_mid+3*1024, Ws_mid+3*1024,
         Wq_mid+4*1024, Wk_mid+4*1024, Wv_mid+4*1024, Ws_mid+4*1024,
         4, xA, nullptr, nullptr, nullptr);
  // pair (6,7) level 1 (UPS input: x1s + xA[inv1]) -> xA (N1 rows)
  pair32(x1s, nullptr, xA, inv1, 2, N1, N0, C,
         Wq_mid+5*1024, Wk_mid+5*1024, Wv_mid+5*1024, Ws_mid+5*1024,
         Wq_mid+6*1024, Wk_mid+6*1024, Wv_mid+6*1024, Ws_mid+6*1024,
         6, xA, nullptr, nullptr, nullptr);
  // pair (8,9): T8 (UPS input: x0s + xA[inv0]), attn8+T9(Cout=1), attn9+head
  k_transformF<<<cdiv(N0,8),256,0,stream>>>(x0s, nullptr, xA, inv0,
                                            Wq_mid+7*1024, Wk_mid+7*1024,
                                            Wv_mid+7*1024, Ws_mid+7*1024,
                                            qb, kvb, sb, N0, C, 2);
  k_attn32_t1<<<cdiv(N0,8),256,0,stream>>>(qb, kvb, sb, rowA, srcsA, metaA,
                                           wr1 + 8*16, wr2 + 8*16,
                                           scale_mid + 8*C, bias_mid + 8*C,
                                           Wq_last, Wk_last, Wv_last, Ws_last,
                                           q1v, k1v, v1v, s1v, N0, invsc);
  {
    float invsc1 = 1.f / sqrtf(3.f);
    k_attn1_head<<<cdiv(N0,256),256,0,stream>>>(q1v, k1v, v1v, s1v, rowA, srcsA, metaA,
                                                wr1 + 9*16, wr2 + 9*16,
                                                scale_last, bias_last,
                                                Wmlp, (float*)d_out, N0, invsc1);
  }
}